// Round 6
// baseline (368.884 us; speedup 1.0000x reference)
//
#include <hip/hip_runtime.h>
#include <math.h>

// EfficientDet postprocess for MI355X — round 12.
// R11 passed (358us, t1=96us). Post-mortem: the 100-step greedy scan on wave 0
// used 4 dependent __shfl round-trips per step (~60cy each on a solo wave,
// nothing overlaps) -> ~50us of the 96. This round makes the scan chain
// cross-lane-free: the 512-bit alive set is REPLICATED in every lane's
// registers (8 x u64); per step = in-register find-first-set (pure VALU) +
// 8 independent uniform LDS reads of rowm[idx] (one latency window, LDS
// broadcast) + 8 ANDs. No shuffles, no ballots in the scan.
// Sort/build/gather/epilogue and all other kernels byte-identical to R11.
// Semantics unchanged: first-alive selection over j>=i suppression rows,
// sticky degenerate refill (self-bit absent -> re-selected), starvation or
// overflow -> exact fallback.

#define NANCH 49104
#define NB 8
#define NC 90
#define NBC 720
#define POSTN 100
#define T1CAP 512
#define WMAX 8          // T1CAP/64 row words
#define CHUNK 512
#define NCH 96          // ceil(49104/512)
#define LCAP 32         // per-(class,chunk) LDS list cap
#define EDGE 0.93f      // P(sigmoid(N(0,1)) >= 0.93) ~ 0.484% -> ~238 +/- 15 per (b,c)
#define PRECHK 2.0f     // sigmoid(2.0)=0.8808 < EDGE: safe cheap pre-filter

// ---------- exact-float helpers (mirror numpy f32 semantics, no FMA) ----------

__device__ __forceinline__ float sigmoid_ref(float x) {
  if (x >= 0.0f) return __fdiv_rn(1.0f, __fadd_rn(1.0f, expf(-x)));
  float e = expf(x);
  return __fdiv_rn(e, __fadd_rn(1.0f, e));
}

__device__ __forceinline__ float iou_ref(float4 a, float4 b) {
  float yy1 = fmaxf(a.x, b.x);
  float xx1 = fmaxf(a.y, b.y);
  float yy2 = fminf(a.z, b.z);
  float xx2 = fminf(a.w, b.w);
  float ih = fmaxf(__fsub_rn(yy2, yy1), 0.0f);
  float iw = fmaxf(__fsub_rn(xx2, xx1), 0.0f);
  float inter = __fmul_rn(ih, iw);
  float a1 = __fmul_rn(__fsub_rn(a.z, a.x), __fsub_rn(a.w, a.y));
  float a2 = __fmul_rn(__fsub_rn(b.z, b.x), __fsub_rn(b.w, b.y));
  float den = __fadd_rn(__fsub_rn(__fadd_rn(a1, a2), inter), 1e-8f);
  return __fdiv_rn(inter, den);
}

// ---------------------------- anchors (+ counter zeroing) ----------------------

__global__ __launch_bounds__(256) void k_anchors(float4* __restrict__ anchors,
                                                 unsigned int* __restrict__ gcnt,
                                                 unsigned int* __restrict__ oflow) {
  int n = blockIdx.x * 256 + threadIdx.x;
  if (n < NBC) { gcnt[n] = 0u; oflow[n] = 0u; }
  if (n >= NANCH) return;
  int l, off;
  if (n < 36864)      { l = 0; off = 0; }
  else if (n < 46080) { l = 1; off = 36864; }
  else if (n < 48384) { l = 2; off = 46080; }
  else if (n < 48960) { l = 3; off = 48384; }
  else                { l = 4; off = 48960; }
  int stride = 8 << l;
  int feat = 64 >> l;
  int r = n - off;
  int cell = r / 9, a = r - cell * 9;
  int iy = cell / feat, ix = cell - iy * feat;
  int isc = a / 3, ir = a - isc * 3;
  // numpy computes half-sizes in float64, then casts to float32
  double base = exp2((double)isc / 3.0) * (double)stride * 4.0;
  double rt = (ir == 0) ? 1.0 : (ir == 1 ? 0.5 : 2.0);
  double sq = sqrt(rt);
  float hh = (float)(base / sq / 2.0);
  float hw = (float)(base * sq / 2.0);
  float cy = __fmul_rn(__fadd_rn((float)iy, 0.5f), (float)stride);
  float cx = __fmul_rn(__fadd_rn((float)ix, 0.5f), (float)stride);
  anchors[n] = make_float4(__fsub_rn(cy, hh), __fsub_rn(cx, hw),
                           __fadd_rn(cy, hh), __fadd_rn(cx, hw));
}

// ---------------------------- decode -------------------------------------------

__global__ __launch_bounds__(256) void k_decode(const float4* __restrict__ deltas,
                                                const float4* __restrict__ anchors,
                                                float4* __restrict__ boxes) {
  int i = blockIdx.x * 256 + threadIdx.x;
  if (i >= NB * NANCH) return;
  int n = i % NANCH;
  float4 a = anchors[n];
  float4 d = deltas[i];
  float ah = __fsub_rn(a.z, a.x);
  float aw = __fsub_rn(a.w, a.y);
  float acy = __fmul_rn(__fadd_rn(a.x, a.z), 0.5f);
  float acx = __fmul_rn(__fadd_rn(a.y, a.w), 0.5f);
  float cy = __fadd_rn(__fmul_rn(d.x, ah), acy);
  float cx = __fadd_rn(__fmul_rn(d.y, aw), acx);
  float h = __fmul_rn(expf(d.z), ah);
  float w = __fmul_rn(expf(d.w), aw);
  float y1 = __fsub_rn(cy, __fmul_rn(h, 0.5f));
  float x1 = __fsub_rn(cx, __fmul_rn(w, 0.5f));
  float y2 = __fadd_rn(cy, __fmul_rn(h, 0.5f));
  float x2 = __fadd_rn(cx, __fmul_rn(w, 0.5f));
  const float inv = 0.001953125f;  // 1/512, exact
  y1 = fminf(fmaxf(__fmul_rn(y1, inv), 0.0f), 1.0f);
  x1 = fminf(fmaxf(__fmul_rn(x1, inv), 0.0f), 1.0f);
  y2 = fminf(fmaxf(__fmul_rn(y2, inv), 0.0f), 1.0f);
  x2 = fminf(fmaxf(__fmul_rn(x2, inv), 0.0f), 1.0f);
  boxes[i] = make_float4(y1, x1, y2, x2);
}

// ------------- candidate scan: LDS-aggregated, 1 reservation atomic ------------
// (verbatim R7/R9/R10/R11-passing kernel)

__global__ __launch_bounds__(256) void k_scan(const float4* __restrict__ logits4,
                                              unsigned long long* __restrict__ gcand,
                                              unsigned int* __restrict__ gcnt,
                                              unsigned int* __restrict__ oflow) {
  int b = blockIdx.y;
  int ch = blockIdx.x;
  int n0 = ch * CHUNK;
  int rows = min(CHUNK, NANCH - n0);
  const float4* base = logits4 + ((size_t)b * NANCH + n0) * 90 / 4;
  int tot4 = rows * 90 / 4;
  int tid = threadIdx.x;

  __shared__ unsigned long long lc[NC * LCAP];  // 23 KB
  __shared__ unsigned int lcnt[NC];
  for (int c = tid; c < NC; c += 256) lcnt[c] = 0u;
  __syncthreads();

  for (int e4 = tid; e4 < tot4; e4 += 1024) {
    float4 v[4];
#pragma unroll
    for (int k = 0; k < 4; k++) {
      int idx = e4 + k * 256;
      if (idx < tot4) v[k] = base[idx];
    }
#pragma unroll
    for (int k = 0; k < 4; k++) {
      int idx = e4 + k * 256;
      if (idx >= tot4) break;
      float xs[4] = {v[k].x, v[k].y, v[k].z, v[k].w};
#pragma unroll
      for (int j = 0; j < 4; j++) {
        float x = xs[j];
        if (x >= PRECHK) {  // skips sigmoid for ~98% of elements
          float s = sigmoid_ref(x);
          if (s >= EDGE) {
            int e = idx * 4 + j;
            int r = e / 90, c = e - r * 90;
            unsigned int pos = atomicAdd(&lcnt[c], 1u);  // LDS atomic (on-CU)
            if (pos < LCAP) {
              int n = n0 + r;
              lc[c * LCAP + pos] =
                  ((unsigned long long)__float_as_uint(s) << 32) |
                  (unsigned int)(65535 - n);  // u64 desc == score desc, n asc
            }
          }
        }
      }
    }
  }
  __syncthreads();

  // reserve + flush: one global atomic per (class,chunk) with candidates
  if (tid < NC) {
    unsigned int cnt = lcnt[tid];
    int bc = b * NC + tid;
    if (cnt > LCAP) {  // ~1e-16 probability: flag bc for exact fallback
      atomicOr(&oflow[bc], 1u);
      cnt = LCAP;
    }
    if (cnt > 0) {
      unsigned int pos0 = atomicAdd(&gcnt[bc], cnt);
      for (unsigned int k = 0; k < cnt; k++) {
        unsigned int p = pos0 + k;
        if (p < T1CAP) gcand[(size_t)bc * T1CAP + p] = lc[tid * LCAP + k];
      }
    }
  }
}

// ------------- tier1: sort + suppression matrix + bitmask greedy scan ----------

__global__ __launch_bounds__(256) void k_nms_t1(
    const unsigned long long* __restrict__ gcand,
    const unsigned int* __restrict__ gcnt, const unsigned int* __restrict__ oflow,
    const float4* __restrict__ boxes, float* __restrict__ sel_s,
    float4* __restrict__ sel_b, int* __restrict__ flags) {
  int bc = blockIdx.x;
  int b = bc / NC;
  int tid = threadIdx.x;
  int lane = tid & 63;
  int wv = tid >> 6;

  __shared__ unsigned long long cand[T1CAP];          // 4 KB
  __shared__ float4 cbox[T1CAP];                      // 8 KB
  __shared__ unsigned long long rowm[T1CAP][WMAX];    // 32 KB
  __shared__ int s_seli[POSTN];
  __shared__ int s_nsel;

  unsigned int cnt = gcnt[bc];
  bool overflow = (cnt > (unsigned)T1CAP) || (oflow[bc] != 0u);
  int M = (int)min(cnt, (unsigned)T1CAP);
  for (int e = tid; e < T1CAP; e += 256)
    cand[e] = (e < M) ? gcand[(size_t)bc * T1CAP + e] : 0ull;
  if (tid == 0) s_nsel = 0;
  __syncthreads();

  // bitonic sort descending (key = score desc, tie idx asc via 65535-n packing)
  // R7-proven 256-thread mapping; adaptive SN (zero-padding beyond M).
  int SN = (M <= 128) ? 128 : (M <= 256) ? 256 : 512;
  int np = SN >> 1;
  for (int k = 2; k <= SN; k <<= 1) {
    for (int j = k >> 1; j > 0; j >>= 1) {
      int t = tid;
      if (t < np) {
        int i = ((t & ~(j - 1)) << 1) | (t & (j - 1));
        int p = i | j;
        unsigned long long a = cand[i], bb = cand[p];
        bool up = ((i & k) == 0);
        if (up ? (a < bb) : (a > bb)) { cand[i] = bb; cand[p] = a; }
      }
      __syncthreads();
    }
  }

  // gather boxes (sorted order) -> LDS; zero-fill tail so j-regs need no guard
  for (int e = tid; e < T1CAP; e += 256) {
    if (e < M) {
      int n = 65535 - (int)(cand[e] & 0xFFFFull);
      cbox[e] = boxes[(size_t)b * NANCH + n];
    } else {
      cbox[e] = make_float4(0.0f, 0.0f, 0.0f, 0.0f);
    }
  }
  __syncthreads();

  // per-lane j-register copies (identical in every wave): jb[w] = cbox[w*64+lane]
  float4 jb[WMAX];
#pragma unroll
  for (int w = 0; w < WMAX; w++) jb[w] = cbox[(w << 6) + lane];

  int W = (M + 63) >> 6;  // active row words

  // build suppression rows: wave wv handles rows i = wv, wv+4, ...
  // row i word w: bit(lane) = j>=i && j<M && iou(box_j, box_i) > 0.5, j=w*64+lane.
  // bit i (self) = iou(bi,bi)>0.5: normal box -> clears itself after selection;
  // zero-area box -> stays alive -> sticky refill (reference semantics).
  for (int i = wv; i < M; i += 4) {
    float4 bi = cbox[i];  // wave-uniform -> LDS broadcast
    int w0 = i >> 6;
    unsigned long long myw = 0ull;
#pragma unroll
    for (int w = 0; w < WMAX; w++) {
      unsigned long long rw = 0ull;
      if (w >= w0 && w < W) {
        int j = (w << 6) + lane;
        bool bit = (j >= i) && (j < M) && (iou_ref(jb[w], bi) > 0.5f);
        rw = __ballot((int)bit);
      }
      if (lane == w) myw = rw;
    }
    if (lane < WMAX) rowm[i][lane] = myw;
  }
  __syncthreads();

  // greedy scan (wave 0): cross-lane-free. The 512-bit alive set lives in
  // every lane's registers (8 x u64, identical values). Per step:
  //   - find-first-set over av[0..7] (pure VALU, no shuffles)
  //   - AND out rowm[idx][0..7]: 8 independent uniform LDS reads (broadcast,
  //     one latency window) + 8 ANDs.
  if (wv == 0) {
    unsigned long long av[WMAX];
#pragma unroll
    for (int w = 0; w < WMAX; w++) {
      int lo = w << 6;
      av[w] = (M >= lo + 64) ? ~0ull
            : (M > lo ? ((1ull << (M - lo)) - 1ull) : 0ull);
    }
    int nsel = 0;
    for (int p = 0; p < POSTN; p++) {
      int idx = -1;
#pragma unroll
      for (int w = 0; w < WMAX; w++) {
        if (idx < 0 && av[w] != 0ull)
          idx = (w << 6) + (__ffsll((unsigned long long)av[w]) - 1);
      }
      if (idx < 0) break;  // starvation -> bad -> fallback
      if (lane == 0) s_seli[p] = idx;
      nsel++;
#pragma unroll
      for (int w = 0; w < WMAX; w++) av[w] &= ~rowm[idx][w];
    }
    if (lane == 0) s_nsel = nsel;
  }
  __syncthreads();

  // valid only if 100 selections completed from a complete (non-overflowed) list
  int ns = s_nsel;
  bool bad = overflow || (ns < POSTN);
  if (tid == 0) flags[bc] = bad ? 1 : 0;
  if (bad) return;
  for (int p = tid; p < POSTN; p += 256) {
    int i = s_seli[p];
    float s0 = __uint_as_float((unsigned int)(cand[i] >> 32));
    float4 bx = cbox[i];
    bool valid = (s0 > 0.2f);  // SCORE_THR gate (always true here: s0>=EDGE)
    sel_s[bc * POSTN + p] = valid ? s0 : 0.0f;
    sel_b[bc * POSTN + p] = valid ? bx : make_float4(0, 0, 0, 0);
  }
}

// -------- flag-all helper (only if workspace too small for scan buffers) -------

__global__ __launch_bounds__(256) void k_flagall(int* __restrict__ flags) {
  int i = blockIdx.x * 256 + threadIdx.x;
  if (i < NBC) flags[i] = 1;
}

// -------- exact fallback: histogram rank-5000 + sort + NMS (rare/never) --------

template <int CAP, int RANK>
__global__ __launch_bounds__(256) void k_nms_fb(const float* __restrict__ logits,
                                                const float4* __restrict__ boxes,
                                                float* __restrict__ sel_s,
                                                float4* __restrict__ sel_b,
                                                const int* __restrict__ flags) {
  int bc = blockIdx.x;
  if (flags[bc] == 0) return;
  int b = bc / NC;
  int c = bc - b * NC;
  int tid = threadIdx.x;

  __shared__ unsigned int s_key[CAP];
  __shared__ unsigned short s_idx[CAP];
  __shared__ __align__(16) unsigned char s_pool[8192];
  __shared__ unsigned int s_bsum[256];
  __shared__ unsigned char s_alive[512];
  __shared__ float4 s_selbox[POSTN];
  __shared__ float s_sels[POSTN];
  __shared__ int s_cnt, s_nsel, s_cutbin;

  const float* lrow = logits + (size_t)b * NANCH * 90 + c;

  unsigned int* hist = (unsigned int*)s_pool;
  for (int e = tid; e < 2048; e += 256) hist[e] = 0u;
  if (tid == 0) { s_cnt = 0; s_nsel = 0; s_cutbin = 0; }
  __syncthreads();

  for (int n = tid; n < NANCH; n += 256) {
    float s = sigmoid_ref(lrow[(size_t)n * 90]);
    int bin = (int)(s * 2048.0f);
    if (bin > 2047) bin = 2047;
    atomicAdd(&hist[bin], 1u);
  }
  __syncthreads();
  unsigned int loc = 0;
#pragma unroll
  for (int k = 0; k < 8; k++) loc += hist[tid * 8 + k];
  s_bsum[tid] = loc;
  __syncthreads();
  if (tid == 0) {
    unsigned int cum = 0;
    int bin = 0;
    bool fnd = false;
    for (int t = 255; t >= 0 && !fnd; t--) {
      if (cum + s_bsum[t] >= (unsigned)RANK) {
        for (int kk = 7; kk >= 0; kk--) {
          unsigned int h = hist[t * 8 + kk];
          if (cum + h >= (unsigned)RANK) { bin = t * 8 + kk; fnd = true; break; }
          cum += h;
        }
      } else {
        cum += s_bsum[t];
      }
    }
    s_cutbin = bin;
  }
  __syncthreads();
  float edge = __fmul_rn((float)s_cutbin, (1.0f / 2048.0f));  // exact

  for (int n = tid; n < NANCH; n += 256) {
    float s = sigmoid_ref(lrow[(size_t)n * 90]);
    if (s >= edge) {
      int pos = atomicAdd(&s_cnt, 1);
      if (pos < CAP) {
        s_key[pos] = __float_as_uint(s);
        s_idx[pos] = (unsigned short)n;
      }
    }
  }
  __syncthreads();
  int M = s_cnt;
  if (M > CAP) M = CAP;
  for (int e = M + tid; e < CAP; e += 256) { s_key[e] = 0u; s_idx[e] = 0xFFFFu; }
  __syncthreads();

  for (int k = 2; k <= CAP; k <<= 1) {
    for (int j = k >> 1; j > 0; j >>= 1) {
      for (int t = tid; t < CAP / 2; t += 256) {
        int i = ((t & ~(j - 1)) << 1) | (t & (j - 1));
        int p = i | j;
        unsigned int ka = s_key[i], kb = s_key[p];
        unsigned short ia = s_idx[i], ib = s_idx[p];
        bool up = ((i & k) == 0);
        bool g = (ka < kb) || (ka == kb && ia > ib);
        bool l = (kb < ka) || (ka == kb && ib > ia);
        if (up ? g : l) {
          s_key[i] = kb; s_key[p] = ka;
          s_idx[i] = ib; s_idx[p] = ia;
        }
      }
      __syncthreads();
    }
  }

  float4* cbox = (float4*)s_pool;
  int L = (M < 5000) ? M : 5000;  // PRE_NMS truncation (stable)
  for (int base = 0; base < L; base += 512) {
    int cn = min(512, L - base);
    int ns0 = s_nsel;
    if (ns0 >= POSTN) break;
    for (int t = tid; t < cn; t += 256) {
      int n = s_idx[base + t];
      float4 bx = boxes[(size_t)b * NANCH + n];
      bool al = true;
      for (int s = 0; s < ns0; s++) {
        if (iou_ref(bx, s_selbox[s]) > 0.5f) { al = false; break; }
      }
      cbox[t] = bx;
      s_alive[t] = al ? 1 : 0;
    }
    __syncthreads();
    for (int i = 0; i < cn; i++) {
      if (s_nsel >= POSTN) break;
      if (!s_alive[i]) continue;
      float4 bi = cbox[i];
      float sc = __uint_as_float(s_key[base + i]);
      if (!(iou_ref(bi, bi) > 0.5f)) {
        if (tid == 0) {
          for (int p = s_nsel; p < POSTN; p++) { s_selbox[p] = bi; s_sels[p] = sc; }
          s_nsel = POSTN;
        }
        __syncthreads();
        break;
      }
      for (int t = tid; t < cn; t += 256) {
        if (t > i && s_alive[t] && iou_ref(cbox[t], bi) > 0.5f) s_alive[t] = 0;
      }
      if (tid == 0) {
        s_selbox[s_nsel] = bi;
        s_sels[s_nsel] = sc;
        s_nsel = s_nsel + 1;
      }
      __syncthreads();
    }
    __syncthreads();
    if (s_nsel >= POSTN) break;
  }
  __syncthreads();
  int ns = s_nsel;
  for (int p = tid; p < POSTN; p += 256) {
    float sc = 0.0f;
    float4 bx = make_float4(0.0f, 0.0f, 0.0f, 0.0f);
    if (p < ns) {
      float s0 = s_sels[p];
      if (s0 > 0.2f) { sc = s0; bx = s_selbox[p]; }
    }
    sel_s[bc * POSTN + p] = sc;
    sel_b[bc * POSTN + p] = bx;
  }
}

// ---------------- per-batch top-100: frontier merge, single-wave ----------------
// (verbatim R9/R10/R11-passing kernel)

__global__ __launch_bounds__(64) void k_final(const float* __restrict__ sel_s,
                                              const float4* __restrict__ sel_b,
                                              float* __restrict__ out) {
  int b = blockIdx.x;
  int tid = threadIdx.x;
  __shared__ float key[9000];
  __shared__ unsigned int win_k[POSTN];
  __shared__ int win_e[POSTN];
  for (int e = tid; e < 9000; e += 64) key[e] = sel_s[(size_t)b * 9000 + e];
  int p0 = 0, p1 = 0;       // frontier ptrs for classes tid and tid+64
  int c1 = tid + 64;        // valid iff c1 < NC (lanes 0..25)
  __syncthreads();
  for (int p = 0; p < POSTN; p++) {
    unsigned long long v = 0ull;
    if (p0 < POSTN) {
      int e = tid * POSTN + p0;
      v = ((unsigned long long)__float_as_uint(key[e]) << 32) |
          (unsigned int)(16383 - e);  // max score, then min flat idx (stable)
    }
    if (c1 < NC && p1 < POSTN) {
      int e = c1 * POSTN + p1;
      unsigned long long v2 = ((unsigned long long)__float_as_uint(key[e]) << 32) |
                              (unsigned int)(16383 - e);
      if (v2 > v) v = v2;
    }
#pragma unroll
    for (int d = 1; d < 64; d <<= 1) {
      unsigned long long o = __shfl_xor(v, d, 64);
      if (o > v) v = o;
    }
    int e = 16383 - (int)(v & 0x3FFFull);
    if (tid == 0) { win_k[p] = (unsigned int)(v >> 32); win_e[p] = e; }
    int cls = e / POSTN;
    int pp = e - cls * POSTN;
    if (cls == tid) p0 = pp + 1;
    else if (cls == c1) p1 = pp + 1;
  }
  __syncthreads();
  for (int p = tid; p < POSTN; p += 64) {
    unsigned int k = win_k[p];
    int e = win_e[p];
    float4 bx = sel_b[(size_t)b * 9000 + e];
    ((float4*)out)[b * POSTN + p] = bx;              // out_b [8,100,4]
    out[3200 + b * POSTN + p] = __uint_as_float(k);  // out_s [8,100]
    out[4000 + b * POSTN + p] = (float)(e / POSTN);  // out_c [8,100]
  }
  int vcnt = 0;
  for (int p = tid; p < POSTN; p += 64) vcnt += (win_k[p] != 0u) ? 1 : 0;
#pragma unroll
  for (int d = 1; d < 64; d <<= 1) vcnt += __shfl_xor(vcnt, d, 64);
  if (tid == 0) out[4800 + b] = (float)vcnt;  // valid [8]
}

// ------------------------------- launcher --------------------------------------

extern "C" void kernel_launch(void* const* d_in, const int* in_sizes, int n_in,
                              void* d_out, int out_size, void* d_ws, size_t ws_size,
                              hipStream_t stream) {
  const float* deltas = (const float*)d_in[0];  // [8,49104,4]
  const float* logits = (const float*)d_in[1];  // [8,49104,90]
  float* out = (float*)d_out;
  char* ws = (char*)d_ws;

  size_t off = 0;
  auto take = [&](size_t bytes) -> char* {
    char* p = ws + off;
    off += (bytes + 255) & ~(size_t)255;
    return p;
  };
  // small/required buffers first so the degraded path fits in ~8.6 MB
  float4* anchors = (float4*)take((size_t)NANCH * 16);
  float4* boxes = (float4*)take((size_t)NB * NANCH * 16);
  float* sel_s = (float*)take((size_t)NBC * POSTN * 4);
  float4* sel_b = (float4*)take((size_t)NBC * POSTN * 16);
  int* flags = (int*)take((size_t)NBC * 4);
  unsigned int* gcnt = (unsigned int*)take((size_t)NBC * 4);
  unsigned int* oflow = (unsigned int*)take((size_t)NBC * 4);
  unsigned long long* gcand =
      (unsigned long long*)take((size_t)NBC * T1CAP * 8);
  bool fits = (off <= ws_size);  // total ~11.5 MB

  k_anchors<<<dim3((NANCH + 255) / 256), dim3(256), 0, stream>>>(anchors, gcnt,
                                                                 oflow);
  k_decode<<<dim3((NB * NANCH + 255) / 256), dim3(256), 0, stream>>>(
      (const float4*)deltas, anchors, boxes);
  if (fits) {
    k_scan<<<dim3(NCH, NB), dim3(256), 0, stream>>>((const float4*)logits,
                                                    gcand, gcnt, oflow);
    k_nms_t1<<<dim3(NBC), dim3(256), 0, stream>>>(gcand, gcnt, oflow, boxes,
                                                  sel_s, sel_b, flags);
  } else {
    k_flagall<<<dim3((NBC + 255) / 256), dim3(256), 0, stream>>>(flags);
  }
  k_nms_fb<8192, 5000><<<dim3(NBC), dim3(256), 0, stream>>>(logits, boxes,
                                                            sel_s, sel_b, flags);
  k_final<<<dim3(NB), dim3(64), 0, stream>>>(sel_s, sel_b, out);
}

// Round 7
// 344.537 us; speedup vs baseline: 1.0707x; 1.0707x over previous
//
#include <hip/hip_runtime.h>
#include <math.h>

// EfficientDet postprocess for MI355X — round 13.
// R12 post-mortem: shfl-free scan didn't move t1 (96->103). Re-derivation
// says the BUILD phase dominates: one-wave-per-row with a ballot per word
// serializes ~55K cy/wave. This round: one-THREAD-per-row build — row bits
// accumulate in a scalar register; all threads read the same cbox[j] per
// step (LDS broadcast, pipelined); no ballots, no cross-lane ops. ~6x less
// issue. Scan keeps R12's register-replicated form + ds_read_b128 row reads
// + next-row (idx+1) prefetch (~85% hit -> LDS latency off critical path).
// Row contents bit-identical to R11/R12 (j>=i, self-bit from iou(bi,bi),
// degenerate-sticky, starvation/overflow -> exact fallback).
// Sort/gather/epilogue and all other kernels byte-identical to R12.

#define NANCH 49104
#define NB 8
#define NC 90
#define NBC 720
#define POSTN 100
#define T1CAP 512
#define WMAX 8          // T1CAP/64 row words
#define CHUNK 512
#define NCH 96          // ceil(49104/512)
#define LCAP 32         // per-(class,chunk) LDS list cap
#define EDGE 0.93f      // P(sigmoid(N(0,1)) >= 0.93) ~ 0.484% -> ~238 +/- 15 per (b,c)
#define PRECHK 2.0f     // sigmoid(2.0)=0.8808 < EDGE: safe cheap pre-filter

// ---------- exact-float helpers (mirror numpy f32 semantics, no FMA) ----------

__device__ __forceinline__ float sigmoid_ref(float x) {
  if (x >= 0.0f) return __fdiv_rn(1.0f, __fadd_rn(1.0f, expf(-x)));
  float e = expf(x);
  return __fdiv_rn(e, __fadd_rn(1.0f, e));
}

__device__ __forceinline__ float iou_ref(float4 a, float4 b) {
  float yy1 = fmaxf(a.x, b.x);
  float xx1 = fmaxf(a.y, b.y);
  float yy2 = fminf(a.z, b.z);
  float xx2 = fminf(a.w, b.w);
  float ih = fmaxf(__fsub_rn(yy2, yy1), 0.0f);
  float iw = fmaxf(__fsub_rn(xx2, xx1), 0.0f);
  float inter = __fmul_rn(ih, iw);
  float a1 = __fmul_rn(__fsub_rn(a.z, a.x), __fsub_rn(a.w, a.y));
  float a2 = __fmul_rn(__fsub_rn(b.z, b.x), __fsub_rn(b.w, b.y));
  float den = __fadd_rn(__fsub_rn(__fadd_rn(a1, a2), inter), 1e-8f);
  return __fdiv_rn(inter, den);
}

// ---------------------------- anchors (+ counter zeroing) ----------------------

__global__ __launch_bounds__(256) void k_anchors(float4* __restrict__ anchors,
                                                 unsigned int* __restrict__ gcnt,
                                                 unsigned int* __restrict__ oflow) {
  int n = blockIdx.x * 256 + threadIdx.x;
  if (n < NBC) { gcnt[n] = 0u; oflow[n] = 0u; }
  if (n >= NANCH) return;
  int l, off;
  if (n < 36864)      { l = 0; off = 0; }
  else if (n < 46080) { l = 1; off = 36864; }
  else if (n < 48384) { l = 2; off = 46080; }
  else if (n < 48960) { l = 3; off = 48384; }
  else                { l = 4; off = 48960; }
  int stride = 8 << l;
  int feat = 64 >> l;
  int r = n - off;
  int cell = r / 9, a = r - cell * 9;
  int iy = cell / feat, ix = cell - iy * feat;
  int isc = a / 3, ir = a - isc * 3;
  // numpy computes half-sizes in float64, then casts to float32
  double base = exp2((double)isc / 3.0) * (double)stride * 4.0;
  double rt = (ir == 0) ? 1.0 : (ir == 1 ? 0.5 : 2.0);
  double sq = sqrt(rt);
  float hh = (float)(base / sq / 2.0);
  float hw = (float)(base * sq / 2.0);
  float cy = __fmul_rn(__fadd_rn((float)iy, 0.5f), (float)stride);
  float cx = __fmul_rn(__fadd_rn((float)ix, 0.5f), (float)stride);
  anchors[n] = make_float4(__fsub_rn(cy, hh), __fsub_rn(cx, hw),
                           __fadd_rn(cy, hh), __fadd_rn(cx, hw));
}

// ---------------------------- decode -------------------------------------------

__global__ __launch_bounds__(256) void k_decode(const float4* __restrict__ deltas,
                                                const float4* __restrict__ anchors,
                                                float4* __restrict__ boxes) {
  int i = blockIdx.x * 256 + threadIdx.x;
  if (i >= NB * NANCH) return;
  int n = i % NANCH;
  float4 a = anchors[n];
  float4 d = deltas[i];
  float ah = __fsub_rn(a.z, a.x);
  float aw = __fsub_rn(a.w, a.y);
  float acy = __fmul_rn(__fadd_rn(a.x, a.z), 0.5f);
  float acx = __fmul_rn(__fadd_rn(a.y, a.w), 0.5f);
  float cy = __fadd_rn(__fmul_rn(d.x, ah), acy);
  float cx = __fadd_rn(__fmul_rn(d.y, aw), acx);
  float h = __fmul_rn(expf(d.z), ah);
  float w = __fmul_rn(expf(d.w), aw);
  float y1 = __fsub_rn(cy, __fmul_rn(h, 0.5f));
  float x1 = __fsub_rn(cx, __fmul_rn(w, 0.5f));
  float y2 = __fadd_rn(cy, __fmul_rn(h, 0.5f));
  float x2 = __fadd_rn(cx, __fmul_rn(w, 0.5f));
  const float inv = 0.001953125f;  // 1/512, exact
  y1 = fminf(fmaxf(__fmul_rn(y1, inv), 0.0f), 1.0f);
  x1 = fminf(fmaxf(__fmul_rn(x1, inv), 0.0f), 1.0f);
  y2 = fminf(fmaxf(__fmul_rn(y2, inv), 0.0f), 1.0f);
  x2 = fminf(fmaxf(__fmul_rn(x2, inv), 0.0f), 1.0f);
  boxes[i] = make_float4(y1, x1, y2, x2);
}

// ------------- candidate scan: LDS-aggregated, 1 reservation atomic ------------
// (verbatim R7..R12-passing kernel)

__global__ __launch_bounds__(256) void k_scan(const float4* __restrict__ logits4,
                                              unsigned long long* __restrict__ gcand,
                                              unsigned int* __restrict__ gcnt,
                                              unsigned int* __restrict__ oflow) {
  int b = blockIdx.y;
  int ch = blockIdx.x;
  int n0 = ch * CHUNK;
  int rows = min(CHUNK, NANCH - n0);
  const float4* base = logits4 + ((size_t)b * NANCH + n0) * 90 / 4;
  int tot4 = rows * 90 / 4;
  int tid = threadIdx.x;

  __shared__ unsigned long long lc[NC * LCAP];  // 23 KB
  __shared__ unsigned int lcnt[NC];
  for (int c = tid; c < NC; c += 256) lcnt[c] = 0u;
  __syncthreads();

  for (int e4 = tid; e4 < tot4; e4 += 1024) {
    float4 v[4];
#pragma unroll
    for (int k = 0; k < 4; k++) {
      int idx = e4 + k * 256;
      if (idx < tot4) v[k] = base[idx];
    }
#pragma unroll
    for (int k = 0; k < 4; k++) {
      int idx = e4 + k * 256;
      if (idx >= tot4) break;
      float xs[4] = {v[k].x, v[k].y, v[k].z, v[k].w};
#pragma unroll
      for (int j = 0; j < 4; j++) {
        float x = xs[j];
        if (x >= PRECHK) {  // skips sigmoid for ~98% of elements
          float s = sigmoid_ref(x);
          if (s >= EDGE) {
            int e = idx * 4 + j;
            int r = e / 90, c = e - r * 90;
            unsigned int pos = atomicAdd(&lcnt[c], 1u);  // LDS atomic (on-CU)
            if (pos < LCAP) {
              int n = n0 + r;
              lc[c * LCAP + pos] =
                  ((unsigned long long)__float_as_uint(s) << 32) |
                  (unsigned int)(65535 - n);  // u64 desc == score desc, n asc
            }
          }
        }
      }
    }
  }
  __syncthreads();

  // reserve + flush: one global atomic per (class,chunk) with candidates
  if (tid < NC) {
    unsigned int cnt = lcnt[tid];
    int bc = b * NC + tid;
    if (cnt > LCAP) {  // ~1e-16 probability: flag bc for exact fallback
      atomicOr(&oflow[bc], 1u);
      cnt = LCAP;
    }
    if (cnt > 0) {
      unsigned int pos0 = atomicAdd(&gcnt[bc], cnt);
      for (unsigned int k = 0; k < cnt; k++) {
        unsigned int p = pos0 + k;
        if (p < T1CAP) gcand[(size_t)bc * T1CAP + p] = lc[tid * LCAP + k];
      }
    }
  }
}

// ------------- tier1: sort + suppression matrix + bitmask greedy scan ----------

__global__ __launch_bounds__(256) void k_nms_t1(
    const unsigned long long* __restrict__ gcand,
    const unsigned int* __restrict__ gcnt, const unsigned int* __restrict__ oflow,
    const float4* __restrict__ boxes, float* __restrict__ sel_s,
    float4* __restrict__ sel_b, int* __restrict__ flags) {
  int bc = blockIdx.x;
  int b = bc / NC;
  int tid = threadIdx.x;
  int lane = tid & 63;
  int wv = tid >> 6;

  __shared__ unsigned long long cand[T1CAP];                        // 4 KB
  __shared__ float4 cbox[T1CAP];                                    // 8 KB
  __shared__ __align__(16) unsigned long long rowm[T1CAP][WMAX];    // 32 KB
  __shared__ int s_seli[POSTN];
  __shared__ int s_nsel;

  unsigned int cnt = gcnt[bc];
  bool overflow = (cnt > (unsigned)T1CAP) || (oflow[bc] != 0u);
  int M = (int)min(cnt, (unsigned)T1CAP);
  for (int e = tid; e < T1CAP; e += 256)
    cand[e] = (e < M) ? gcand[(size_t)bc * T1CAP + e] : 0ull;
  if (tid == 0) s_nsel = 0;
  __syncthreads();

  // bitonic sort descending (key = score desc, tie idx asc via 65535-n packing)
  // R7-proven 256-thread mapping; adaptive SN (zero-padding beyond M).
  int SN = (M <= 128) ? 128 : (M <= 256) ? 256 : 512;
  int np = SN >> 1;
  for (int k = 2; k <= SN; k <<= 1) {
    for (int j = k >> 1; j > 0; j >>= 1) {
      int t = tid;
      if (t < np) {
        int i = ((t & ~(j - 1)) << 1) | (t & (j - 1));
        int p = i | j;
        unsigned long long a = cand[i], bb = cand[p];
        bool up = ((i & k) == 0);
        if (up ? (a < bb) : (a > bb)) { cand[i] = bb; cand[p] = a; }
      }
      __syncthreads();
    }
  }

  // gather boxes (sorted order) -> LDS
  for (int e = tid; e < T1CAP; e += 256) {
    if (e < M) {
      int n = 65535 - (int)(cand[e] & 0xFFFFull);
      cbox[e] = boxes[(size_t)b * NANCH + n];
    } else {
      cbox[e] = make_float4(0.0f, 0.0f, 0.0f, 0.0f);
    }
  }
  __syncthreads();

  int W = (M + 63) >> 6;  // active row words

  // build suppression rows: one THREAD per row (strided pass if M>256).
  // Row i word w: bit jj = iou(box_j, box_i) > 0.5 for j = w*64+jj in [i, M).
  // Every thread reads the SAME cbox[j] per inner step -> LDS broadcast,
  // reads independent -> pipelined. No ballots, no cross-lane ops. Bits are
  // accumulated in a scalar register (static indexing). Self-bit i comes from
  // iou(bi,bi): normal box -> set (clears itself after selection); zero-area
  // box -> clear -> sticky refill (reference semantics).
  for (int i = tid; i < M; i += 256) {
    float4 bi = cbox[i];
    int wi = i >> 6;
    unsigned int bl = (unsigned int)(i & 63);
#pragma unroll
    for (int w = 0; w < WMAX; w++) {
      unsigned long long acc = 0ull;
      if (w >= wi && w < W) {
        int jmax = min(64, M - (w << 6));
#pragma unroll 4
        for (int jj = 0; jj < jmax; jj++) {
          float4 bj = cbox[(w << 6) + jj];  // uniform address -> broadcast
          if (iou_ref(bj, bi) > 0.5f) acc |= (1ull << jj);
        }
        if (w == wi) acc &= (~0ull) << bl;
      }
      rowm[i][w] = acc;
    }
  }
  __syncthreads();

  // greedy scan (wave 0): cross-lane-free, register-replicated alive set
  // (R12-proven). Rows read as 4x ds_read_b128; next-row (idx+1) prefetched —
  // it is the next selection ~85% of the time, taking the LDS round-trip off
  // the critical path. Miss path = plain load (semantics identical).
  if (wv == 0) {
    unsigned long long av[WMAX];
#pragma unroll
    for (int w = 0; w < WMAX; w++) {
      int lo = w << 6;
      av[w] = (M >= lo + 64) ? ~0ull
            : (M > lo ? ((1ull << (M - lo)) - 1ull) : 0ull);
    }
    int nsel = 0;
    int pidx = -1;
    unsigned long long pr[WMAX];
#pragma unroll
    for (int w = 0; w < WMAX; w++) pr[w] = 0ull;
    for (int p = 0; p < POSTN; p++) {
      int idx = -1;
#pragma unroll
      for (int w = 0; w < WMAX; w++) {
        if (idx < 0 && av[w] != 0ull)
          idx = (w << 6) + (__ffsll((unsigned long long)av[w]) - 1);
      }
      if (idx < 0) break;  // starvation -> bad -> fallback
      if (lane == 0) s_seli[p] = idx;
      nsel++;
      if (idx == pidx) {
#pragma unroll
        for (int w = 0; w < WMAX; w++) av[w] &= ~pr[w];
      } else {
        const ulonglong2* rp = (const ulonglong2*)(&rowm[idx][0]);
#pragma unroll
        for (int w = 0; w < 4; w++) {
          ulonglong2 rr = rp[w];
          av[2 * w] &= ~rr.x;
          av[2 * w + 1] &= ~rr.y;
        }
      }
      int nx = idx + 1;
      if (nx < M) {
        const ulonglong2* rp2 = (const ulonglong2*)(&rowm[nx][0]);
#pragma unroll
        for (int w = 0; w < 4; w++) {
          ulonglong2 rr = rp2[w];
          pr[2 * w] = rr.x;
          pr[2 * w + 1] = rr.y;
        }
        pidx = nx;
      } else {
        pidx = -1;
      }
    }
    if (lane == 0) s_nsel = nsel;
  }
  __syncthreads();

  // valid only if 100 selections completed from a complete (non-overflowed) list
  int ns = s_nsel;
  bool bad = overflow || (ns < POSTN);
  if (tid == 0) flags[bc] = bad ? 1 : 0;
  if (bad) return;
  for (int p = tid; p < POSTN; p += 256) {
    int i = s_seli[p];
    float s0 = __uint_as_float((unsigned int)(cand[i] >> 32));
    float4 bx = cbox[i];
    bool valid = (s0 > 0.2f);  // SCORE_THR gate (always true here: s0>=EDGE)
    sel_s[bc * POSTN + p] = valid ? s0 : 0.0f;
    sel_b[bc * POSTN + p] = valid ? bx : make_float4(0, 0, 0, 0);
  }
}

// -------- flag-all helper (only if workspace too small for scan buffers) -------

__global__ __launch_bounds__(256) void k_flagall(int* __restrict__ flags) {
  int i = blockIdx.x * 256 + threadIdx.x;
  if (i < NBC) flags[i] = 1;
}

// -------- exact fallback: histogram rank-5000 + sort + NMS (rare/never) --------

template <int CAP, int RANK>
__global__ __launch_bounds__(256) void k_nms_fb(const float* __restrict__ logits,
                                                const float4* __restrict__ boxes,
                                                float* __restrict__ sel_s,
                                                float4* __restrict__ sel_b,
                                                const int* __restrict__ flags) {
  int bc = blockIdx.x;
  if (flags[bc] == 0) return;
  int b = bc / NC;
  int c = bc - b * NC;
  int tid = threadIdx.x;

  __shared__ unsigned int s_key[CAP];
  __shared__ unsigned short s_idx[CAP];
  __shared__ __align__(16) unsigned char s_pool[8192];
  __shared__ unsigned int s_bsum[256];
  __shared__ unsigned char s_alive[512];
  __shared__ float4 s_selbox[POSTN];
  __shared__ float s_sels[POSTN];
  __shared__ int s_cnt, s_nsel, s_cutbin;

  const float* lrow = logits + (size_t)b * NANCH * 90 + c;

  unsigned int* hist = (unsigned int*)s_pool;
  for (int e = tid; e < 2048; e += 256) hist[e] = 0u;
  if (tid == 0) { s_cnt = 0; s_nsel = 0; s_cutbin = 0; }
  __syncthreads();

  for (int n = tid; n < NANCH; n += 256) {
    float s = sigmoid_ref(lrow[(size_t)n * 90]);
    int bin = (int)(s * 2048.0f);
    if (bin > 2047) bin = 2047;
    atomicAdd(&hist[bin], 1u);
  }
  __syncthreads();
  unsigned int loc = 0;
#pragma unroll
  for (int k = 0; k < 8; k++) loc += hist[tid * 8 + k];
  s_bsum[tid] = loc;
  __syncthreads();
  if (tid == 0) {
    unsigned int cum = 0;
    int bin = 0;
    bool fnd = false;
    for (int t = 255; t >= 0 && !fnd; t--) {
      if (cum + s_bsum[t] >= (unsigned)RANK) {
        for (int kk = 7; kk >= 0; kk--) {
          unsigned int h = hist[t * 8 + kk];
          if (cum + h >= (unsigned)RANK) { bin = t * 8 + kk; fnd = true; break; }
          cum += h;
        }
      } else {
        cum += s_bsum[t];
      }
    }
    s_cutbin = bin;
  }
  __syncthreads();
  float edge = __fmul_rn((float)s_cutbin, (1.0f / 2048.0f));  // exact

  for (int n = tid; n < NANCH; n += 256) {
    float s = sigmoid_ref(lrow[(size_t)n * 90]);
    if (s >= edge) {
      int pos = atomicAdd(&s_cnt, 1);
      if (pos < CAP) {
        s_key[pos] = __float_as_uint(s);
        s_idx[pos] = (unsigned short)n;
      }
    }
  }
  __syncthreads();
  int M = s_cnt;
  if (M > CAP) M = CAP;
  for (int e = M + tid; e < CAP; e += 256) { s_key[e] = 0u; s_idx[e] = 0xFFFFu; }
  __syncthreads();

  for (int k = 2; k <= CAP; k <<= 1) {
    for (int j = k >> 1; j > 0; j >>= 1) {
      for (int t = tid; t < CAP / 2; t += 256) {
        int i = ((t & ~(j - 1)) << 1) | (t & (j - 1));
        int p = i | j;
        unsigned int ka = s_key[i], kb = s_key[p];
        unsigned short ia = s_idx[i], ib = s_idx[p];
        bool up = ((i & k) == 0);
        bool g = (ka < kb) || (ka == kb && ia > ib);
        bool l = (kb < ka) || (ka == kb && ib > ia);
        if (up ? g : l) {
          s_key[i] = kb; s_key[p] = ka;
          s_idx[i] = ib; s_idx[p] = ia;
        }
      }
      __syncthreads();
    }
  }

  float4* cbox = (float4*)s_pool;
  int L = (M < 5000) ? M : 5000;  // PRE_NMS truncation (stable)
  for (int base = 0; base < L; base += 512) {
    int cn = min(512, L - base);
    int ns0 = s_nsel;
    if (ns0 >= POSTN) break;
    for (int t = tid; t < cn; t += 256) {
      int n = s_idx[base + t];
      float4 bx = boxes[(size_t)b * NANCH + n];
      bool al = true;
      for (int s = 0; s < ns0; s++) {
        if (iou_ref(bx, s_selbox[s]) > 0.5f) { al = false; break; }
      }
      cbox[t] = bx;
      s_alive[t] = al ? 1 : 0;
    }
    __syncthreads();
    for (int i = 0; i < cn; i++) {
      if (s_nsel >= POSTN) break;
      if (!s_alive[i]) continue;
      float4 bi = cbox[i];
      float sc = __uint_as_float(s_key[base + i]);
      if (!(iou_ref(bi, bi) > 0.5f)) {
        if (tid == 0) {
          for (int p = s_nsel; p < POSTN; p++) { s_selbox[p] = bi; s_sels[p] = sc; }
          s_nsel = POSTN;
        }
        __syncthreads();
        break;
      }
      for (int t = tid; t < cn; t += 256) {
        if (t > i && s_alive[t] && iou_ref(cbox[t], bi) > 0.5f) s_alive[t] = 0;
      }
      if (tid == 0) {
        s_selbox[s_nsel] = bi;
        s_sels[s_nsel] = sc;
        s_nsel = s_nsel + 1;
      }
      __syncthreads();
    }
    __syncthreads();
    if (s_nsel >= POSTN) break;
  }
  __syncthreads();
  int ns = s_nsel;
  for (int p = tid; p < POSTN; p += 256) {
    float sc = 0.0f;
    float4 bx = make_float4(0.0f, 0.0f, 0.0f, 0.0f);
    if (p < ns) {
      float s0 = s_sels[p];
      if (s0 > 0.2f) { sc = s0; bx = s_selbox[p]; }
    }
    sel_s[bc * POSTN + p] = sc;
    sel_b[bc * POSTN + p] = bx;
  }
}

// ---------------- per-batch top-100: frontier merge, single-wave ----------------
// (verbatim R9..R12-passing kernel)

__global__ __launch_bounds__(64) void k_final(const float* __restrict__ sel_s,
                                              const float4* __restrict__ sel_b,
                                              float* __restrict__ out) {
  int b = blockIdx.x;
  int tid = threadIdx.x;
  __shared__ float key[9000];
  __shared__ unsigned int win_k[POSTN];
  __shared__ int win_e[POSTN];
  for (int e = tid; e < 9000; e += 64) key[e] = sel_s[(size_t)b * 9000 + e];
  int p0 = 0, p1 = 0;       // frontier ptrs for classes tid and tid+64
  int c1 = tid + 64;        // valid iff c1 < NC (lanes 0..25)
  __syncthreads();
  for (int p = 0; p < POSTN; p++) {
    unsigned long long v = 0ull;
    if (p0 < POSTN) {
      int e = tid * POSTN + p0;
      v = ((unsigned long long)__float_as_uint(key[e]) << 32) |
          (unsigned int)(16383 - e);  // max score, then min flat idx (stable)
    }
    if (c1 < NC && p1 < POSTN) {
      int e = c1 * POSTN + p1;
      unsigned long long v2 = ((unsigned long long)__float_as_uint(key[e]) << 32) |
                              (unsigned int)(16383 - e);
      if (v2 > v) v = v2;
    }
#pragma unroll
    for (int d = 1; d < 64; d <<= 1) {
      unsigned long long o = __shfl_xor(v, d, 64);
      if (o > v) v = o;
    }
    int e = 16383 - (int)(v & 0x3FFFull);
    if (tid == 0) { win_k[p] = (unsigned int)(v >> 32); win_e[p] = e; }
    int cls = e / POSTN;
    int pp = e - cls * POSTN;
    if (cls == tid) p0 = pp + 1;
    else if (cls == c1) p1 = pp + 1;
  }
  __syncthreads();
  for (int p = tid; p < POSTN; p += 64) {
    unsigned int k = win_k[p];
    int e = win_e[p];
    float4 bx = sel_b[(size_t)b * 9000 + e];
    ((float4*)out)[b * POSTN + p] = bx;              // out_b [8,100,4]
    out[3200 + b * POSTN + p] = __uint_as_float(k);  // out_s [8,100]
    out[4000 + b * POSTN + p] = (float)(e / POSTN);  // out_c [8,100]
  }
  int vcnt = 0;
  for (int p = tid; p < POSTN; p += 64) vcnt += (win_k[p] != 0u) ? 1 : 0;
#pragma unroll
  for (int d = 1; d < 64; d <<= 1) vcnt += __shfl_xor(vcnt, d, 64);
  if (tid == 0) out[4800 + b] = (float)vcnt;  // valid [8]
}

// ------------------------------- launcher --------------------------------------

extern "C" void kernel_launch(void* const* d_in, const int* in_sizes, int n_in,
                              void* d_out, int out_size, void* d_ws, size_t ws_size,
                              hipStream_t stream) {
  const float* deltas = (const float*)d_in[0];  // [8,49104,4]
  const float* logits = (const float*)d_in[1];  // [8,49104,90]
  float* out = (float*)d_out;
  char* ws = (char*)d_ws;

  size_t off = 0;
  auto take = [&](size_t bytes) -> char* {
    char* p = ws + off;
    off += (bytes + 255) & ~(size_t)255;
    return p;
  };
  // small/required buffers first so the degraded path fits in ~8.6 MB
  float4* anchors = (float4*)take((size_t)NANCH * 16);
  float4* boxes = (float4*)take((size_t)NB * NANCH * 16);
  float* sel_s = (float*)take((size_t)NBC * POSTN * 4);
  float4* sel_b = (float4*)take((size_t)NBC * POSTN * 16);
  int* flags = (int*)take((size_t)NBC * 4);
  unsigned int* gcnt = (unsigned int*)take((size_t)NBC * 4);
  unsigned int* oflow = (unsigned int*)take((size_t)NBC * 4);
  unsigned long long* gcand =
      (unsigned long long*)take((size_t)NBC * T1CAP * 8);
  bool fits = (off <= ws_size);  // total ~11.5 MB

  k_anchors<<<dim3((NANCH + 255) / 256), dim3(256), 0, stream>>>(anchors, gcnt,
                                                                 oflow);
  k_decode<<<dim3((NB * NANCH + 255) / 256), dim3(256), 0, stream>>>(
      (const float4*)deltas, anchors, boxes);
  if (fits) {
    k_scan<<<dim3(NCH, NB), dim3(256), 0, stream>>>((const float4*)logits,
                                                    gcand, gcnt, oflow);
    k_nms_t1<<<dim3(NBC), dim3(256), 0, stream>>>(gcand, gcnt, oflow, boxes,
                                                  sel_s, sel_b, flags);
  } else {
    k_flagall<<<dim3((NBC + 255) / 256), dim3(256), 0, stream>>>(flags);
  }
  k_nms_fb<8192, 5000><<<dim3(NBC), dim3(256), 0, stream>>>(logits, boxes,
                                                            sel_s, sel_b, flags);
  k_final<<<dim3(NB), dim3(64), 0, stream>>>(sel_s, sel_b, out);
}

// Round 8
// 323.428 us; speedup vs baseline: 1.1405x; 1.0653x over previous
//
#include <hip/hip_runtime.h>
#include <math.h>

// EfficientDet postprocess for MI355X — round 14.
// R13 passed (344.5us); all top-5 dispatches are now harness fills (83us).
// Remaining controllable: scan ~25 (BW floor), t1 ~20, final ~15-20, rest ~10.
// This round parallelizes the two remaining serial chains:
//   k_final: 100 serial frontier steps (6-deep shfl u64 butterfly each) ->
//     exact stable top-100 via monotone histogram cut + bitonic sort of ~160
//     candidates (frontier merge of desc-sorted rows == top-100 of packed keys
//     (bits<<32 | 16383-e), same packing as proven kernel). Overflow of the
//     cut bin (>512 cands, needs fb-zeros — statistically never) falls back
//     in-kernel to the R4-proven serial frontier verbatim. 256 threads;
//     launcher updated to dim3(256) to match (R8 lesson).
//   k_nms_t1 scan: self-only rows (suppress nobody but self; one ballot per
//     row-word at build) are bulk-selected with in-register bit ops; only
//     ~10-15 non-self-only selections per block pay the LDS row-AND.
//     Sticky-degenerate and starvation/overflow semantics unchanged.
// All other kernels byte-identical to R13 (passing build).

#define NANCH 49104
#define NB 8
#define NC 90
#define NBC 720
#define POSTN 100
#define T1CAP 512
#define WMAX 8          // T1CAP/64 row words
#define CHUNK 512
#define NCH 96          // ceil(49104/512)
#define LCAP 32         // per-(class,chunk) LDS list cap
#define EDGE 0.93f      // P(sigmoid(N(0,1)) >= 0.93) ~ 0.484% -> ~238 +/- 15 per (b,c)
#define PRECHK 2.0f     // sigmoid(2.0)=0.8808 < EDGE: safe cheap pre-filter

// ---------- exact-float helpers (mirror numpy f32 semantics, no FMA) ----------

__device__ __forceinline__ float sigmoid_ref(float x) {
  if (x >= 0.0f) return __fdiv_rn(1.0f, __fadd_rn(1.0f, expf(-x)));
  float e = expf(x);
  return __fdiv_rn(e, __fadd_rn(1.0f, e));
}

__device__ __forceinline__ float iou_ref(float4 a, float4 b) {
  float yy1 = fmaxf(a.x, b.x);
  float xx1 = fmaxf(a.y, b.y);
  float yy2 = fminf(a.z, b.z);
  float xx2 = fminf(a.w, b.w);
  float ih = fmaxf(__fsub_rn(yy2, yy1), 0.0f);
  float iw = fmaxf(__fsub_rn(xx2, xx1), 0.0f);
  float inter = __fmul_rn(ih, iw);
  float a1 = __fmul_rn(__fsub_rn(a.z, a.x), __fsub_rn(a.w, a.y));
  float a2 = __fmul_rn(__fsub_rn(b.z, b.x), __fsub_rn(b.w, b.y));
  float den = __fadd_rn(__fsub_rn(__fadd_rn(a1, a2), inter), 1e-8f);
  return __fdiv_rn(inter, den);
}

// ---------------------------- anchors (+ counter zeroing) ----------------------

__global__ __launch_bounds__(256) void k_anchors(float4* __restrict__ anchors,
                                                 unsigned int* __restrict__ gcnt,
                                                 unsigned int* __restrict__ oflow) {
  int n = blockIdx.x * 256 + threadIdx.x;
  if (n < NBC) { gcnt[n] = 0u; oflow[n] = 0u; }
  if (n >= NANCH) return;
  int l, off;
  if (n < 36864)      { l = 0; off = 0; }
  else if (n < 46080) { l = 1; off = 36864; }
  else if (n < 48384) { l = 2; off = 46080; }
  else if (n < 48960) { l = 3; off = 48384; }
  else                { l = 4; off = 48960; }
  int stride = 8 << l;
  int feat = 64 >> l;
  int r = n - off;
  int cell = r / 9, a = r - cell * 9;
  int iy = cell / feat, ix = cell - iy * feat;
  int isc = a / 3, ir = a - isc * 3;
  // numpy computes half-sizes in float64, then casts to float32
  double base = exp2((double)isc / 3.0) * (double)stride * 4.0;
  double rt = (ir == 0) ? 1.0 : (ir == 1 ? 0.5 : 2.0);
  double sq = sqrt(rt);
  float hh = (float)(base / sq / 2.0);
  float hw = (float)(base * sq / 2.0);
  float cy = __fmul_rn(__fadd_rn((float)iy, 0.5f), (float)stride);
  float cx = __fmul_rn(__fadd_rn((float)ix, 0.5f), (float)stride);
  anchors[n] = make_float4(__fsub_rn(cy, hh), __fsub_rn(cx, hw),
                           __fadd_rn(cy, hh), __fadd_rn(cx, hw));
}

// ---------------------------- decode -------------------------------------------

__global__ __launch_bounds__(256) void k_decode(const float4* __restrict__ deltas,
                                                const float4* __restrict__ anchors,
                                                float4* __restrict__ boxes) {
  int i = blockIdx.x * 256 + threadIdx.x;
  if (i >= NB * NANCH) return;
  int n = i % NANCH;
  float4 a = anchors[n];
  float4 d = deltas[i];
  float ah = __fsub_rn(a.z, a.x);
  float aw = __fsub_rn(a.w, a.y);
  float acy = __fmul_rn(__fadd_rn(a.x, a.z), 0.5f);
  float acx = __fmul_rn(__fadd_rn(a.y, a.w), 0.5f);
  float cy = __fadd_rn(__fmul_rn(d.x, ah), acy);
  float cx = __fadd_rn(__fmul_rn(d.y, aw), acx);
  float h = __fmul_rn(expf(d.z), ah);
  float w = __fmul_rn(expf(d.w), aw);
  float y1 = __fsub_rn(cy, __fmul_rn(h, 0.5f));
  float x1 = __fsub_rn(cx, __fmul_rn(w, 0.5f));
  float y2 = __fadd_rn(cy, __fmul_rn(h, 0.5f));
  float x2 = __fadd_rn(cx, __fmul_rn(w, 0.5f));
  const float inv = 0.001953125f;  // 1/512, exact
  y1 = fminf(fmaxf(__fmul_rn(y1, inv), 0.0f), 1.0f);
  x1 = fminf(fmaxf(__fmul_rn(x1, inv), 0.0f), 1.0f);
  y2 = fminf(fmaxf(__fmul_rn(y2, inv), 0.0f), 1.0f);
  x2 = fminf(fmaxf(__fmul_rn(x2, inv), 0.0f), 1.0f);
  boxes[i] = make_float4(y1, x1, y2, x2);
}

// ------------- candidate scan: LDS-aggregated, 1 reservation atomic ------------
// (verbatim R7..R13-passing kernel)

__global__ __launch_bounds__(256) void k_scan(const float4* __restrict__ logits4,
                                              unsigned long long* __restrict__ gcand,
                                              unsigned int* __restrict__ gcnt,
                                              unsigned int* __restrict__ oflow) {
  int b = blockIdx.y;
  int ch = blockIdx.x;
  int n0 = ch * CHUNK;
  int rows = min(CHUNK, NANCH - n0);
  const float4* base = logits4 + ((size_t)b * NANCH + n0) * 90 / 4;
  int tot4 = rows * 90 / 4;
  int tid = threadIdx.x;

  __shared__ unsigned long long lc[NC * LCAP];  // 23 KB
  __shared__ unsigned int lcnt[NC];
  for (int c = tid; c < NC; c += 256) lcnt[c] = 0u;
  __syncthreads();

  for (int e4 = tid; e4 < tot4; e4 += 1024) {
    float4 v[4];
#pragma unroll
    for (int k = 0; k < 4; k++) {
      int idx = e4 + k * 256;
      if (idx < tot4) v[k] = base[idx];
    }
#pragma unroll
    for (int k = 0; k < 4; k++) {
      int idx = e4 + k * 256;
      if (idx >= tot4) break;
      float xs[4] = {v[k].x, v[k].y, v[k].z, v[k].w};
#pragma unroll
      for (int j = 0; j < 4; j++) {
        float x = xs[j];
        if (x >= PRECHK) {  // skips sigmoid for ~98% of elements
          float s = sigmoid_ref(x);
          if (s >= EDGE) {
            int e = idx * 4 + j;
            int r = e / 90, c = e - r * 90;
            unsigned int pos = atomicAdd(&lcnt[c], 1u);  // LDS atomic (on-CU)
            if (pos < LCAP) {
              int n = n0 + r;
              lc[c * LCAP + pos] =
                  ((unsigned long long)__float_as_uint(s) << 32) |
                  (unsigned int)(65535 - n);  // u64 desc == score desc, n asc
            }
          }
        }
      }
    }
  }
  __syncthreads();

  // reserve + flush: one global atomic per (class,chunk) with candidates
  if (tid < NC) {
    unsigned int cnt = lcnt[tid];
    int bc = b * NC + tid;
    if (cnt > LCAP) {  // ~1e-16 probability: flag bc for exact fallback
      atomicOr(&oflow[bc], 1u);
      cnt = LCAP;
    }
    if (cnt > 0) {
      unsigned int pos0 = atomicAdd(&gcnt[bc], cnt);
      for (unsigned int k = 0; k < cnt; k++) {
        unsigned int p = pos0 + k;
        if (p < T1CAP) gcand[(size_t)bc * T1CAP + p] = lc[tid * LCAP + k];
      }
    }
  }
}

// ------------- tier1: sort + suppression matrix + bitmask greedy scan ----------

__global__ __launch_bounds__(256) void k_nms_t1(
    const unsigned long long* __restrict__ gcand,
    const unsigned int* __restrict__ gcnt, const unsigned int* __restrict__ oflow,
    const float4* __restrict__ boxes, float* __restrict__ sel_s,
    float4* __restrict__ sel_b, int* __restrict__ flags) {
  int bc = blockIdx.x;
  int b = bc / NC;
  int tid = threadIdx.x;
  int lane = tid & 63;
  int wv = tid >> 6;

  __shared__ unsigned long long cand[T1CAP];                        // 4 KB
  __shared__ float4 cbox[T1CAP];                                    // 8 KB
  __shared__ __align__(16) unsigned long long rowm[T1CAP][WMAX];    // 32 KB
  __shared__ unsigned long long sonly[WMAX];  // bit j: row j is self-only
  __shared__ int s_seli[POSTN];
  __shared__ int s_nsel;

  unsigned int cnt = gcnt[bc];
  bool overflow = (cnt > (unsigned)T1CAP) || (oflow[bc] != 0u);
  int M = (int)min(cnt, (unsigned)T1CAP);
  for (int e = tid; e < T1CAP; e += 256)
    cand[e] = (e < M) ? gcand[(size_t)bc * T1CAP + e] : 0ull;
  if (tid == 0) s_nsel = 0;
  if (tid < WMAX) sonly[tid] = 0ull;
  __syncthreads();

  // bitonic sort descending (key = score desc, tie idx asc via 65535-n packing)
  // R7-proven 256-thread mapping; adaptive SN (zero-padding beyond M).
  int SN = (M <= 128) ? 128 : (M <= 256) ? 256 : 512;
  int np = SN >> 1;
  for (int k = 2; k <= SN; k <<= 1) {
    for (int j = k >> 1; j > 0; j >>= 1) {
      int t = tid;
      if (t < np) {
        int i = ((t & ~(j - 1)) << 1) | (t & (j - 1));
        int p = i | j;
        unsigned long long a = cand[i], bb = cand[p];
        bool up = ((i & k) == 0);
        if (up ? (a < bb) : (a > bb)) { cand[i] = bb; cand[p] = a; }
      }
      __syncthreads();
    }
  }

  // gather boxes (sorted order) -> LDS
  for (int e = tid; e < T1CAP; e += 256) {
    if (e < M) {
      int n = 65535 - (int)(cand[e] & 0xFFFFull);
      cbox[e] = boxes[(size_t)b * NANCH + n];
    } else {
      cbox[e] = make_float4(0.0f, 0.0f, 0.0f, 0.0f);
    }
  }
  __syncthreads();

  int W = (M + 63) >> 6;  // active row words

  // build suppression rows: one THREAD per row (R13-proven). Row i word w:
  // bit jj = iou(box_j, box_i) > 0.5 for j = w*64+jj in [i, M). Uniform
  // cbox[j] reads -> LDS broadcast, pipelined. Self-bit i from iou(bi,bi):
  // normal box -> set (clears itself on selection); zero-area -> clear ->
  // sticky refill (reference semantics). Additionally record per-row
  // "self-only" (row == exactly its self bit) via one wave ballot per pass:
  // within a wave, i>>6 is uniform (i = tid + 256*iter).
  for (int i = tid; i < M; i += 256) {
    float4 bi = cbox[i];
    int wi = i >> 6;
    unsigned int bl = (unsigned int)(i & 63);
    bool so = true;
#pragma unroll
    for (int w = 0; w < WMAX; w++) {
      unsigned long long acc = 0ull;
      if (w >= wi && w < W) {
        int jmax = min(64, M - (w << 6));
#pragma unroll 4
        for (int jj = 0; jj < jmax; jj++) {
          float4 bj = cbox[(w << 6) + jj];  // uniform address -> broadcast
          if (iou_ref(bj, bi) > 0.5f) acc |= (1ull << jj);
        }
        if (w == wi) acc &= (~0ull) << bl;
      }
      rowm[i][w] = acc;
      so = so && (acc == ((w == wi) ? (1ull << bl) : 0ull));
    }
    unsigned long long bal = __ballot((int)so);
    if (lane == 0) sonly[i >> 6] = bal;  // lane 0 active whenever any lane is
  }
  __syncthreads();

  // greedy scan (wave 0): register-replicated alive set (R12-proven) +
  // self-only bulk path. A run of alive self-only bits below the first
  // non-self-only alive bit is selected en-masse (each removes only itself;
  // order preserved) with pure VALU. Only non-self-only selections read rowm.
  if (wv == 0) {
    unsigned long long av[WMAX];
#pragma unroll
    for (int w = 0; w < WMAX; w++) {
      int lo = w << 6;
      av[w] = (M >= lo + 64) ? ~0ull
            : (M > lo ? ((1ull << (M - lo)) - 1ull) : 0ull);
    }
    unsigned long long sor[WMAX];
#pragma unroll
    for (int w = 0; w < WMAX; w++) sor[w] = sonly[w];
    int nsel = 0;
    while (nsel < POSTN) {
      int w = -1;
#pragma unroll
      for (int ww = 0; ww < WMAX; ww++)
        if (w < 0 && av[ww] != 0ull) w = ww;
      if (w < 0) break;  // starvation -> bad -> fallback
      unsigned long long m = av[w];
      unsigned long long bad = m & ~sor[w];
      // alive self-only bits strictly below the lowest non-self-only alive bit
      unsigned long long pre =
          bad ? (m & ((bad & (0ull - bad)) - 1ull)) : m;
      if (pre != 0ull) {
        while (pre != 0ull && nsel < POSTN) {
          int bit = __ffsll((unsigned long long)pre) - 1;
          if (lane == 0) s_seli[nsel] = (w << 6) + bit;
          nsel++;
          pre &= pre - 1ull;
          av[w] &= ~(1ull << bit);
        }
      } else {
        int bit = __ffsll((unsigned long long)m) - 1;
        int idx = (w << 6) + bit;
        if (lane == 0) s_seli[nsel] = idx;
        nsel++;
#pragma unroll
        for (int ww = 0; ww < WMAX; ww++) av[ww] &= ~rowm[idx][ww];
      }
    }
    if (lane == 0) s_nsel = nsel;
  }
  __syncthreads();

  // valid only if 100 selections completed from a complete (non-overflowed) list
  int ns = s_nsel;
  bool bad = overflow || (ns < POSTN);
  if (tid == 0) flags[bc] = bad ? 1 : 0;
  if (bad) return;
  for (int p = tid; p < POSTN; p += 256) {
    int i = s_seli[p];
    float s0 = __uint_as_float((unsigned int)(cand[i] >> 32));
    float4 bx = cbox[i];
    bool valid = (s0 > 0.2f);  // SCORE_THR gate (always true here: s0>=EDGE)
    sel_s[bc * POSTN + p] = valid ? s0 : 0.0f;
    sel_b[bc * POSTN + p] = valid ? bx : make_float4(0, 0, 0, 0);
  }
}

// -------- flag-all helper (only if workspace too small for scan buffers) -------

__global__ __launch_bounds__(256) void k_flagall(int* __restrict__ flags) {
  int i = blockIdx.x * 256 + threadIdx.x;
  if (i < NBC) flags[i] = 1;
}

// -------- exact fallback: histogram rank-5000 + sort + NMS (rare/never) --------

template <int CAP, int RANK>
__global__ __launch_bounds__(256) void k_nms_fb(const float* __restrict__ logits,
                                                const float4* __restrict__ boxes,
                                                float* __restrict__ sel_s,
                                                float4* __restrict__ sel_b,
                                                const int* __restrict__ flags) {
  int bc = blockIdx.x;
  if (flags[bc] == 0) return;
  int b = bc / NC;
  int c = bc - b * NC;
  int tid = threadIdx.x;

  __shared__ unsigned int s_key[CAP];
  __shared__ unsigned short s_idx[CAP];
  __shared__ __align__(16) unsigned char s_pool[8192];
  __shared__ unsigned int s_bsum[256];
  __shared__ unsigned char s_alive[512];
  __shared__ float4 s_selbox[POSTN];
  __shared__ float s_sels[POSTN];
  __shared__ int s_cnt, s_nsel, s_cutbin;

  const float* lrow = logits + (size_t)b * NANCH * 90 + c;

  unsigned int* hist = (unsigned int*)s_pool;
  for (int e = tid; e < 2048; e += 256) hist[e] = 0u;
  if (tid == 0) { s_cnt = 0; s_nsel = 0; s_cutbin = 0; }
  __syncthreads();

  for (int n = tid; n < NANCH; n += 256) {
    float s = sigmoid_ref(lrow[(size_t)n * 90]);
    int bin = (int)(s * 2048.0f);
    if (bin > 2047) bin = 2047;
    atomicAdd(&hist[bin], 1u);
  }
  __syncthreads();
  unsigned int loc = 0;
#pragma unroll
  for (int k = 0; k < 8; k++) loc += hist[tid * 8 + k];
  s_bsum[tid] = loc;
  __syncthreads();
  if (tid == 0) {
    unsigned int cum = 0;
    int bin = 0;
    bool fnd = false;
    for (int t = 255; t >= 0 && !fnd; t--) {
      if (cum + s_bsum[t] >= (unsigned)RANK) {
        for (int kk = 7; kk >= 0; kk--) {
          unsigned int h = hist[t * 8 + kk];
          if (cum + h >= (unsigned)RANK) { bin = t * 8 + kk; fnd = true; break; }
          cum += h;
        }
      } else {
        cum += s_bsum[t];
      }
    }
    s_cutbin = bin;
  }
  __syncthreads();
  float edge = __fmul_rn((float)s_cutbin, (1.0f / 2048.0f));  // exact

  for (int n = tid; n < NANCH; n += 256) {
    float s = sigmoid_ref(lrow[(size_t)n * 90]);
    if (s >= edge) {
      int pos = atomicAdd(&s_cnt, 1);
      if (pos < CAP) {
        s_key[pos] = __float_as_uint(s);
        s_idx[pos] = (unsigned short)n;
      }
    }
  }
  __syncthreads();
  int M = s_cnt;
  if (M > CAP) M = CAP;
  for (int e = M + tid; e < CAP; e += 256) { s_key[e] = 0u; s_idx[e] = 0xFFFFu; }
  __syncthreads();

  for (int k = 2; k <= CAP; k <<= 1) {
    for (int j = k >> 1; j > 0; j >>= 1) {
      for (int t = tid; t < CAP / 2; t += 256) {
        int i = ((t & ~(j - 1)) << 1) | (t & (j - 1));
        int p = i | j;
        unsigned int ka = s_key[i], kb = s_key[p];
        unsigned short ia = s_idx[i], ib = s_idx[p];
        bool up = ((i & k) == 0);
        bool g = (ka < kb) || (ka == kb && ia > ib);
        bool l = (kb < ka) || (ka == kb && ib > ia);
        if (up ? g : l) {
          s_key[i] = kb; s_key[p] = ka;
          s_idx[i] = ib; s_idx[p] = ia;
        }
      }
      __syncthreads();
    }
  }

  float4* cbox = (float4*)s_pool;
  int L = (M < 5000) ? M : 5000;  // PRE_NMS truncation (stable)
  for (int base = 0; base < L; base += 512) {
    int cn = min(512, L - base);
    int ns0 = s_nsel;
    if (ns0 >= POSTN) break;
    for (int t = tid; t < cn; t += 256) {
      int n = s_idx[base + t];
      float4 bx = boxes[(size_t)b * NANCH + n];
      bool al = true;
      for (int s = 0; s < ns0; s++) {
        if (iou_ref(bx, s_selbox[s]) > 0.5f) { al = false; break; }
      }
      cbox[t] = bx;
      s_alive[t] = al ? 1 : 0;
    }
    __syncthreads();
    for (int i = 0; i < cn; i++) {
      if (s_nsel >= POSTN) break;
      if (!s_alive[i]) continue;
      float4 bi = cbox[i];
      float sc = __uint_as_float(s_key[base + i]);
      if (!(iou_ref(bi, bi) > 0.5f)) {
        if (tid == 0) {
          for (int p = s_nsel; p < POSTN; p++) { s_selbox[p] = bi; s_sels[p] = sc; }
          s_nsel = POSTN;
        }
        __syncthreads();
        break;
      }
      for (int t = tid; t < cn; t += 256) {
        if (t > i && s_alive[t] && iou_ref(cbox[t], bi) > 0.5f) s_alive[t] = 0;
      }
      if (tid == 0) {
        s_selbox[s_nsel] = bi;
        s_sels[s_nsel] = sc;
        s_nsel = s_nsel + 1;
      }
      __syncthreads();
    }
    __syncthreads();
    if (s_nsel >= POSTN) break;
  }
  __syncthreads();
  int ns = s_nsel;
  for (int p = tid; p < POSTN; p += 256) {
    float sc = 0.0f;
    float4 bx = make_float4(0.0f, 0.0f, 0.0f, 0.0f);
    if (p < ns) {
      float s0 = s_sels[p];
      if (s0 > 0.2f) { sc = s0; bx = s_selbox[p]; }
    }
    sel_s[bc * POSTN + p] = sc;
    sel_b[bc * POSTN + p] = bx;
  }
}

// ---------------- per-batch top-100: histogram cut + bitonic (parallel) --------
// Frontier merge of 90 desc-sorted rows == stable top-100 of the 9000 packed
// keys (score_bits<<32 | 16383-e): k-way merge of sorted lists emits global
// descending key order, and within a class earlier position -> larger key.
// Fast path: monotone 4096-bin histogram over score bits, rank-100 bin cut,
// collect candidates (bin >= cut, superset of top-100 by monotonicity), one
// bitonic sort, take first 100. If the cut bin overflows 512 candidates
// (needs massive fb-produced ties — statistically never) fall back to the
// R4-proven serial frontier merge verbatim.

__global__ __launch_bounds__(256) void k_final(const float* __restrict__ sel_s,
                                               const float4* __restrict__ sel_b,
                                               float* __restrict__ out) {
  int b = blockIdx.x;
  int tid = threadIdx.x;
  __shared__ __align__(16) unsigned char pool[36864];
  __shared__ unsigned int win_k[POSTN];
  __shared__ int win_e[POSTN];
  __shared__ unsigned int csum[256];
  __shared__ int s_cut, s_cnt;

  const float* srow = sel_s + (size_t)b * 9000;
  unsigned int* hist = (unsigned int*)pool;                        // [4096]
  unsigned long long* ckey = (unsigned long long*)(pool + 16384);  // [512]

  for (int e = tid; e < 4096; e += 256) hist[e] = 0u;
  if (tid == 0) s_cnt = 0;
  __syncthreads();

  // monotone bin: scores in [0.5,1] get 2^-12-mantissa resolution (2048 bins),
  // below 0.5 coarse (bits>>20 < 1008 < 2048). bin(1.0f) clamps to 4095.
  for (int e = tid; e < 9000; e += 256) {
    unsigned int bits = __float_as_uint(srow[e]);
    int bin = (bits >= 0x3F000000u)
                  ? min(4095, (int)(2048u + ((bits - 0x3F000000u) >> 12)))
                  : (int)(bits >> 20);
    atomicAdd(&hist[bin], 1u);
  }
  __syncthreads();

  unsigned int loc = 0;
#pragma unroll
  for (int k = 0; k < 16; k++) loc += hist[tid * 16 + k];
  csum[tid] = loc;
  __syncthreads();

  if (tid == 0) {
    unsigned int cum = 0;
    int cut = 0;
    bool fnd = false;
    for (int t = 255; t >= 0 && !fnd; t--) {
      if (cum + csum[t] >= (unsigned)POSTN) {
        for (int kk = 15; kk >= 0; kk--) {
          int bn = t * 16 + kk;
          unsigned int h = hist[bn];
          if (cum + h >= (unsigned)POSTN) { cut = bn; fnd = true; break; }
          cum += h;
        }
      } else {
        cum += csum[t];
      }
    }
    s_cut = cut;  // 9000 entries >= 100 -> always found
  }
  __syncthreads();
  int cut = s_cut;

  for (int e = tid; e < 9000; e += 256) {
    unsigned int bits = __float_as_uint(srow[e]);
    int bin = (bits >= 0x3F000000u)
                  ? min(4095, (int)(2048u + ((bits - 0x3F000000u) >> 12)))
                  : (int)(bits >> 20);
    if (bin >= cut) {
      int pos = atomicAdd(&s_cnt, 1);
      if (pos < 512)
        ckey[pos] = ((unsigned long long)bits << 32) | (unsigned int)(16383 - e);
    }
  }
  __syncthreads();
  int cnt = s_cnt;

  if (cnt <= 512) {
    int SN = (cnt <= 256) ? 256 : 512;
    for (int e = tid; e < SN; e += 256)
      if (e >= cnt) ckey[e] = 0ull;  // pads sort below all real keys
    __syncthreads();
    for (int k = 2; k <= SN; k <<= 1) {
      for (int j = k >> 1; j > 0; j >>= 1) {
        int t = tid;
        if (t < (SN >> 1)) {
          int i = ((t & ~(j - 1)) << 1) | (t & (j - 1));
          int p = i | j;
          unsigned long long a = ckey[i], bb = ckey[p];
          bool up = ((i & k) == 0);
          if (up ? (a < bb) : (a > bb)) { ckey[i] = bb; ckey[p] = a; }
        }
        __syncthreads();
      }
    }
    if (tid < POSTN) {
      unsigned long long v = ckey[tid];
      win_k[tid] = (unsigned int)(v >> 32);
      win_e[tid] = 16383 - (int)(v & 0x3FFFull);
    }
  } else {
    // overflow (statistically never): R4-proven serial frontier merge
    float* key = (float*)pool;                                      // [9000]
    int* ptr = (int*)(pool + 36032);                                // [90]
    unsigned long long* wred = (unsigned long long*)(pool + 36416); // [4]
    for (int e = tid; e < 9000; e += 256) key[e] = srow[e];
    if (tid < NC) ptr[tid] = 0;
    __syncthreads();
    int lane = tid & 63, wid = tid >> 6;
    for (int p = 0; p < POSTN; p++) {
      unsigned long long v = 0ull;
      if (tid < NC) {
        int pp = ptr[tid];
        if (pp < POSTN) {
          int e = tid * POSTN + pp;
          v = ((unsigned long long)__float_as_uint(key[e]) << 32) |
              (unsigned int)(16383 - e);
        }
      }
      for (int d = 32; d > 0; d >>= 1) {
        unsigned long long o = __shfl_down(v, (unsigned)d, 64);
        if (o > v) v = o;
      }
      if (lane == 0) wred[wid] = v;
      __syncthreads();
      if (tid == 0) {
        unsigned long long w2 = wred[0];
        if (wred[1] > w2) w2 = wred[1];
        int e = 16383 - (int)(w2 & 0x3FFFull);
        win_k[p] = (unsigned int)(w2 >> 32);
        win_e[p] = e;
        ptr[e / POSTN] = (e % POSTN) + 1;
      }
      __syncthreads();
    }
  }
  __syncthreads();

  for (int p = tid; p < POSTN; p += 256) {
    unsigned int k = win_k[p];
    int e = win_e[p];
    float4 bx = sel_b[(size_t)b * 9000 + e];
    ((float4*)out)[b * POSTN + p] = bx;              // out_b [8,100,4]
    out[3200 + b * POSTN + p] = __uint_as_float(k);  // out_s [8,100]
    out[4000 + b * POSTN + p] = (float)(e / POSTN);  // out_c [8,100]
  }
  if (tid == 0) {
    int v = 0;
    for (int p = 0; p < POSTN; p++) v += (win_k[p] != 0u) ? 1 : 0;
    out[4800 + b] = (float)v;  // valid [8]
  }
}

// ------------------------------- launcher --------------------------------------

extern "C" void kernel_launch(void* const* d_in, const int* in_sizes, int n_in,
                              void* d_out, int out_size, void* d_ws, size_t ws_size,
                              hipStream_t stream) {
  const float* deltas = (const float*)d_in[0];  // [8,49104,4]
  const float* logits = (const float*)d_in[1];  // [8,49104,90]
  float* out = (float*)d_out;
  char* ws = (char*)d_ws;

  size_t off = 0;
  auto take = [&](size_t bytes) -> char* {
    char* p = ws + off;
    off += (bytes + 255) & ~(size_t)255;
    return p;
  };
  // small/required buffers first so the degraded path fits in ~8.6 MB
  float4* anchors = (float4*)take((size_t)NANCH * 16);
  float4* boxes = (float4*)take((size_t)NB * NANCH * 16);
  float* sel_s = (float*)take((size_t)NBC * POSTN * 4);
  float4* sel_b = (float4*)take((size_t)NBC * POSTN * 16);
  int* flags = (int*)take((size_t)NBC * 4);
  unsigned int* gcnt = (unsigned int*)take((size_t)NBC * 4);
  unsigned int* oflow = (unsigned int*)take((size_t)NBC * 4);
  unsigned long long* gcand =
      (unsigned long long*)take((size_t)NBC * T1CAP * 8);
  bool fits = (off <= ws_size);  // total ~11.5 MB

  k_anchors<<<dim3((NANCH + 255) / 256), dim3(256), 0, stream>>>(anchors, gcnt,
                                                                 oflow);
  k_decode<<<dim3((NB * NANCH + 255) / 256), dim3(256), 0, stream>>>(
      (const float4*)deltas, anchors, boxes);
  if (fits) {
    k_scan<<<dim3(NCH, NB), dim3(256), 0, stream>>>((const float4*)logits,
                                                    gcand, gcnt, oflow);
    k_nms_t1<<<dim3(NBC), dim3(256), 0, stream>>>(gcand, gcnt, oflow, boxes,
                                                  sel_s, sel_b, flags);
  } else {
    k_flagall<<<dim3((NBC + 255) / 256), dim3(256), 0, stream>>>(flags);
  }
  k_nms_fb<8192, 5000><<<dim3(NBC), dim3(256), 0, stream>>>(logits, boxes,
                                                            sel_s, sel_b, flags);
  k_final<<<dim3(NB), dim3(256), 0, stream>>>(sel_s, sel_b, out);
}

// Round 9
// 320.196 us; speedup vs baseline: 1.1521x; 1.0101x over previous
//
#include <hip/hip_runtime.h>
#include <math.h>

// EfficientDet postprocess for MI355X — round 15.
// R14 passed (323us); t1 back on top at 83.6us. Cross-round reconciliation
// (R6:104 w/ 55 sort stages, R7:75 w/ 45, R14:83 w/ 36 + build + fast scan)
// pins the bitonic sort at ~1.2us/stage (~45us): each stage is a dependent
// LDS->barrier chain at ~3 blocks/CU. This round replaces the sort with
// RANK-AND-SCATTER: keys are unique u64s, so descending position ==
// #{j: key_j > key_i}. One uniform-broadcast-read loop per thread
// (ulonglong2 pairs), scatter scand[rank]=key, copy back. 36 barrier-stages
// -> 3 barriers. scand aliases rowm storage (written only later by build).
// Order identical to the bitonic comparator (full u64 desc = score desc,
// idx asc). Everything else byte-identical to R14 (passing build):
// build w/ self-only ballot, bulk-select scan, histogram k_final, etc.

#define NANCH 49104
#define NB 8
#define NC 90
#define NBC 720
#define POSTN 100
#define T1CAP 512
#define WMAX 8          // T1CAP/64 row words
#define CHUNK 512
#define NCH 96          // ceil(49104/512)
#define LCAP 32         // per-(class,chunk) LDS list cap
#define EDGE 0.93f      // P(sigmoid(N(0,1)) >= 0.93) ~ 0.484% -> ~238 +/- 15 per (b,c)
#define PRECHK 2.0f     // sigmoid(2.0)=0.8808 < EDGE: safe cheap pre-filter

// ---------- exact-float helpers (mirror numpy f32 semantics, no FMA) ----------

__device__ __forceinline__ float sigmoid_ref(float x) {
  if (x >= 0.0f) return __fdiv_rn(1.0f, __fadd_rn(1.0f, expf(-x)));
  float e = expf(x);
  return __fdiv_rn(e, __fadd_rn(1.0f, e));
}

__device__ __forceinline__ float iou_ref(float4 a, float4 b) {
  float yy1 = fmaxf(a.x, b.x);
  float xx1 = fmaxf(a.y, b.y);
  float yy2 = fminf(a.z, b.z);
  float xx2 = fminf(a.w, b.w);
  float ih = fmaxf(__fsub_rn(yy2, yy1), 0.0f);
  float iw = fmaxf(__fsub_rn(xx2, xx1), 0.0f);
  float inter = __fmul_rn(ih, iw);
  float a1 = __fmul_rn(__fsub_rn(a.z, a.x), __fsub_rn(a.w, a.y));
  float a2 = __fmul_rn(__fsub_rn(b.z, b.x), __fsub_rn(b.w, b.y));
  float den = __fadd_rn(__fsub_rn(__fadd_rn(a1, a2), inter), 1e-8f);
  return __fdiv_rn(inter, den);
}

// ---------------------------- anchors (+ counter zeroing) ----------------------

__global__ __launch_bounds__(256) void k_anchors(float4* __restrict__ anchors,
                                                 unsigned int* __restrict__ gcnt,
                                                 unsigned int* __restrict__ oflow) {
  int n = blockIdx.x * 256 + threadIdx.x;
  if (n < NBC) { gcnt[n] = 0u; oflow[n] = 0u; }
  if (n >= NANCH) return;
  int l, off;
  if (n < 36864)      { l = 0; off = 0; }
  else if (n < 46080) { l = 1; off = 36864; }
  else if (n < 48384) { l = 2; off = 46080; }
  else if (n < 48960) { l = 3; off = 48384; }
  else                { l = 4; off = 48960; }
  int stride = 8 << l;
  int feat = 64 >> l;
  int r = n - off;
  int cell = r / 9, a = r - cell * 9;
  int iy = cell / feat, ix = cell - iy * feat;
  int isc = a / 3, ir = a - isc * 3;
  // numpy computes half-sizes in float64, then casts to float32
  double base = exp2((double)isc / 3.0) * (double)stride * 4.0;
  double rt = (ir == 0) ? 1.0 : (ir == 1 ? 0.5 : 2.0);
  double sq = sqrt(rt);
  float hh = (float)(base / sq / 2.0);
  float hw = (float)(base * sq / 2.0);
  float cy = __fmul_rn(__fadd_rn((float)iy, 0.5f), (float)stride);
  float cx = __fmul_rn(__fadd_rn((float)ix, 0.5f), (float)stride);
  anchors[n] = make_float4(__fsub_rn(cy, hh), __fsub_rn(cx, hw),
                           __fadd_rn(cy, hh), __fadd_rn(cx, hw));
}

// ---------------------------- decode -------------------------------------------

__global__ __launch_bounds__(256) void k_decode(const float4* __restrict__ deltas,
                                                const float4* __restrict__ anchors,
                                                float4* __restrict__ boxes) {
  int i = blockIdx.x * 256 + threadIdx.x;
  if (i >= NB * NANCH) return;
  int n = i % NANCH;
  float4 a = anchors[n];
  float4 d = deltas[i];
  float ah = __fsub_rn(a.z, a.x);
  float aw = __fsub_rn(a.w, a.y);
  float acy = __fmul_rn(__fadd_rn(a.x, a.z), 0.5f);
  float acx = __fmul_rn(__fadd_rn(a.y, a.w), 0.5f);
  float cy = __fadd_rn(__fmul_rn(d.x, ah), acy);
  float cx = __fadd_rn(__fmul_rn(d.y, aw), acx);
  float h = __fmul_rn(expf(d.z), ah);
  float w = __fmul_rn(expf(d.w), aw);
  float y1 = __fsub_rn(cy, __fmul_rn(h, 0.5f));
  float x1 = __fsub_rn(cx, __fmul_rn(w, 0.5f));
  float y2 = __fadd_rn(cy, __fmul_rn(h, 0.5f));
  float x2 = __fadd_rn(cx, __fmul_rn(w, 0.5f));
  const float inv = 0.001953125f;  // 1/512, exact
  y1 = fminf(fmaxf(__fmul_rn(y1, inv), 0.0f), 1.0f);
  x1 = fminf(fmaxf(__fmul_rn(x1, inv), 0.0f), 1.0f);
  y2 = fminf(fmaxf(__fmul_rn(y2, inv), 0.0f), 1.0f);
  x2 = fminf(fmaxf(__fmul_rn(x2, inv), 0.0f), 1.0f);
  boxes[i] = make_float4(y1, x1, y2, x2);
}

// ------------- candidate scan: LDS-aggregated, 1 reservation atomic ------------
// (verbatim R7..R14-passing kernel)

__global__ __launch_bounds__(256) void k_scan(const float4* __restrict__ logits4,
                                              unsigned long long* __restrict__ gcand,
                                              unsigned int* __restrict__ gcnt,
                                              unsigned int* __restrict__ oflow) {
  int b = blockIdx.y;
  int ch = blockIdx.x;
  int n0 = ch * CHUNK;
  int rows = min(CHUNK, NANCH - n0);
  const float4* base = logits4 + ((size_t)b * NANCH + n0) * 90 / 4;
  int tot4 = rows * 90 / 4;
  int tid = threadIdx.x;

  __shared__ unsigned long long lc[NC * LCAP];  // 23 KB
  __shared__ unsigned int lcnt[NC];
  for (int c = tid; c < NC; c += 256) lcnt[c] = 0u;
  __syncthreads();

  for (int e4 = tid; e4 < tot4; e4 += 1024) {
    float4 v[4];
#pragma unroll
    for (int k = 0; k < 4; k++) {
      int idx = e4 + k * 256;
      if (idx < tot4) v[k] = base[idx];
    }
#pragma unroll
    for (int k = 0; k < 4; k++) {
      int idx = e4 + k * 256;
      if (idx >= tot4) break;
      float xs[4] = {v[k].x, v[k].y, v[k].z, v[k].w};
#pragma unroll
      for (int j = 0; j < 4; j++) {
        float x = xs[j];
        if (x >= PRECHK) {  // skips sigmoid for ~98% of elements
          float s = sigmoid_ref(x);
          if (s >= EDGE) {
            int e = idx * 4 + j;
            int r = e / 90, c = e - r * 90;
            unsigned int pos = atomicAdd(&lcnt[c], 1u);  // LDS atomic (on-CU)
            if (pos < LCAP) {
              int n = n0 + r;
              lc[c * LCAP + pos] =
                  ((unsigned long long)__float_as_uint(s) << 32) |
                  (unsigned int)(65535 - n);  // u64 desc == score desc, n asc
            }
          }
        }
      }
    }
  }
  __syncthreads();

  // reserve + flush: one global atomic per (class,chunk) with candidates
  if (tid < NC) {
    unsigned int cnt = lcnt[tid];
    int bc = b * NC + tid;
    if (cnt > LCAP) {  // ~1e-16 probability: flag bc for exact fallback
      atomicOr(&oflow[bc], 1u);
      cnt = LCAP;
    }
    if (cnt > 0) {
      unsigned int pos0 = atomicAdd(&gcnt[bc], cnt);
      for (unsigned int k = 0; k < cnt; k++) {
        unsigned int p = pos0 + k;
        if (p < T1CAP) gcand[(size_t)bc * T1CAP + p] = lc[tid * LCAP + k];
      }
    }
  }
}

// ------ tier1: rank-sort + suppression matrix + bitmask greedy scan ------------

__global__ __launch_bounds__(256) void k_nms_t1(
    const unsigned long long* __restrict__ gcand,
    const unsigned int* __restrict__ gcnt, const unsigned int* __restrict__ oflow,
    const float4* __restrict__ boxes, float* __restrict__ sel_s,
    float4* __restrict__ sel_b, int* __restrict__ flags) {
  int bc = blockIdx.x;
  int b = bc / NC;
  int tid = threadIdx.x;
  int lane = tid & 63;
  int wv = tid >> 6;

  __shared__ __align__(16) unsigned long long cand[T1CAP];          // 4 KB
  __shared__ float4 cbox[T1CAP];                                    // 8 KB
  __shared__ __align__(16) unsigned long long rowm[T1CAP][WMAX];    // 32 KB
  __shared__ unsigned long long sonly[WMAX];  // bit j: row j is self-only
  __shared__ int s_seli[POSTN];
  __shared__ int s_nsel;

  unsigned int cnt = gcnt[bc];
  bool overflow = (cnt > (unsigned)T1CAP) || (oflow[bc] != 0u);
  int M = (int)min(cnt, (unsigned)T1CAP);
  for (int e = tid; e < T1CAP; e += 256)
    cand[e] = (e < M) ? gcand[(size_t)bc * T1CAP + e] : 0ull;
  if (tid == 0) s_nsel = 0;
  if (tid < WMAX) sonly[tid] = 0ull;
  __syncthreads();

  // RANK-SORT (replaces 36-stage bitonic): keys unique (distinct packed idx),
  // descending position == #{j: key_j > key_i}. Uniform ulonglong2 broadcast
  // reads; scatter to scand (aliases rowm storage — build writes rowm only
  // after the copy-back). Order == full-u64 desc == score desc, idx asc.
  unsigned long long* scand = &rowm[0][0];  // first 4 KB of rowm
  {
    int half = M >> 1;
    const ulonglong2* cp = (const ulonglong2*)cand;
    for (int i = tid; i < M; i += 256) {
      unsigned long long ki = cand[i];
      int rk = 0;
      for (int j2 = 0; j2 < half; j2++) {
        ulonglong2 kk = cp[j2];
        rk += (kk.x > ki) ? 1 : 0;
        rk += (kk.y > ki) ? 1 : 0;
      }
      if (M & 1) rk += (cand[M - 1] > ki) ? 1 : 0;
      scand[rk] = ki;
    }
  }
  __syncthreads();
  for (int e = tid; e < M; e += 256) cand[e] = scand[e];
  __syncthreads();

  // gather boxes (sorted order) -> LDS
  for (int e = tid; e < T1CAP; e += 256) {
    if (e < M) {
      int n = 65535 - (int)(cand[e] & 0xFFFFull);
      cbox[e] = boxes[(size_t)b * NANCH + n];
    } else {
      cbox[e] = make_float4(0.0f, 0.0f, 0.0f, 0.0f);
    }
  }
  __syncthreads();

  int W = (M + 63) >> 6;  // active row words

  // build suppression rows: one THREAD per row (R13-proven). Row i word w:
  // bit jj = iou(box_j, box_i) > 0.5 for j = w*64+jj in [i, M). Uniform
  // cbox[j] reads -> LDS broadcast, pipelined. Self-bit i from iou(bi,bi):
  // normal box -> set (clears itself on selection); zero-area -> clear ->
  // sticky refill (reference semantics). Per-row "self-only" recorded via
  // one wave ballot per pass (i>>6 uniform within a wave).
  for (int i = tid; i < M; i += 256) {
    float4 bi = cbox[i];
    int wi = i >> 6;
    unsigned int bl = (unsigned int)(i & 63);
    bool so = true;
#pragma unroll
    for (int w = 0; w < WMAX; w++) {
      unsigned long long acc = 0ull;
      if (w >= wi && w < W) {
        int jmax = min(64, M - (w << 6));
#pragma unroll 4
        for (int jj = 0; jj < jmax; jj++) {
          float4 bj = cbox[(w << 6) + jj];  // uniform address -> broadcast
          if (iou_ref(bj, bi) > 0.5f) acc |= (1ull << jj);
        }
        if (w == wi) acc &= (~0ull) << bl;
      }
      rowm[i][w] = acc;
      so = so && (acc == ((w == wi) ? (1ull << bl) : 0ull));
    }
    unsigned long long bal = __ballot((int)so);
    if (lane == 0) sonly[i >> 6] = bal;  // lane 0 active whenever any lane is
  }
  __syncthreads();

  // greedy scan (wave 0): register-replicated alive set (R12-proven) +
  // self-only bulk path (R14-proven). A run of alive self-only bits below the
  // first non-self-only alive bit is selected en-masse (each removes only
  // itself; order preserved). Only non-self-only selections read rowm.
  if (wv == 0) {
    unsigned long long av[WMAX];
#pragma unroll
    for (int w = 0; w < WMAX; w++) {
      int lo = w << 6;
      av[w] = (M >= lo + 64) ? ~0ull
            : (M > lo ? ((1ull << (M - lo)) - 1ull) : 0ull);
    }
    unsigned long long sor[WMAX];
#pragma unroll
    for (int w = 0; w < WMAX; w++) sor[w] = sonly[w];
    int nsel = 0;
    while (nsel < POSTN) {
      int w = -1;
#pragma unroll
      for (int ww = 0; ww < WMAX; ww++)
        if (w < 0 && av[ww] != 0ull) w = ww;
      if (w < 0) break;  // starvation -> bad -> fallback
      unsigned long long m = av[w];
      unsigned long long bad = m & ~sor[w];
      // alive self-only bits strictly below the lowest non-self-only alive bit
      unsigned long long pre =
          bad ? (m & ((bad & (0ull - bad)) - 1ull)) : m;
      if (pre != 0ull) {
        while (pre != 0ull && nsel < POSTN) {
          int bit = __ffsll((unsigned long long)pre) - 1;
          if (lane == 0) s_seli[nsel] = (w << 6) + bit;
          nsel++;
          pre &= pre - 1ull;
          av[w] &= ~(1ull << bit);
        }
      } else {
        int bit = __ffsll((unsigned long long)m) - 1;
        int idx = (w << 6) + bit;
        if (lane == 0) s_seli[nsel] = idx;
        nsel++;
#pragma unroll
        for (int ww = 0; ww < WMAX; ww++) av[ww] &= ~rowm[idx][ww];
      }
    }
    if (lane == 0) s_nsel = nsel;
  }
  __syncthreads();

  // valid only if 100 selections completed from a complete (non-overflowed) list
  int ns = s_nsel;
  bool bad = overflow || (ns < POSTN);
  if (tid == 0) flags[bc] = bad ? 1 : 0;
  if (bad) return;
  for (int p = tid; p < POSTN; p += 256) {
    int i = s_seli[p];
    float s0 = __uint_as_float((unsigned int)(cand[i] >> 32));
    float4 bx = cbox[i];
    bool valid = (s0 > 0.2f);  // SCORE_THR gate (always true here: s0>=EDGE)
    sel_s[bc * POSTN + p] = valid ? s0 : 0.0f;
    sel_b[bc * POSTN + p] = valid ? bx : make_float4(0, 0, 0, 0);
  }
}

// -------- flag-all helper (only if workspace too small for scan buffers) -------

__global__ __launch_bounds__(256) void k_flagall(int* __restrict__ flags) {
  int i = blockIdx.x * 256 + threadIdx.x;
  if (i < NBC) flags[i] = 1;
}

// -------- exact fallback: histogram rank-5000 + sort + NMS (rare/never) --------

template <int CAP, int RANK>
__global__ __launch_bounds__(256) void k_nms_fb(const float* __restrict__ logits,
                                                const float4* __restrict__ boxes,
                                                float* __restrict__ sel_s,
                                                float4* __restrict__ sel_b,
                                                const int* __restrict__ flags) {
  int bc = blockIdx.x;
  if (flags[bc] == 0) return;
  int b = bc / NC;
  int c = bc - b * NC;
  int tid = threadIdx.x;

  __shared__ unsigned int s_key[CAP];
  __shared__ unsigned short s_idx[CAP];
  __shared__ __align__(16) unsigned char s_pool[8192];
  __shared__ unsigned int s_bsum[256];
  __shared__ unsigned char s_alive[512];
  __shared__ float4 s_selbox[POSTN];
  __shared__ float s_sels[POSTN];
  __shared__ int s_cnt, s_nsel, s_cutbin;

  const float* lrow = logits + (size_t)b * NANCH * 90 + c;

  unsigned int* hist = (unsigned int*)s_pool;
  for (int e = tid; e < 2048; e += 256) hist[e] = 0u;
  if (tid == 0) { s_cnt = 0; s_nsel = 0; s_cutbin = 0; }
  __syncthreads();

  for (int n = tid; n < NANCH; n += 256) {
    float s = sigmoid_ref(lrow[(size_t)n * 90]);
    int bin = (int)(s * 2048.0f);
    if (bin > 2047) bin = 2047;
    atomicAdd(&hist[bin], 1u);
  }
  __syncthreads();
  unsigned int loc = 0;
#pragma unroll
  for (int k = 0; k < 8; k++) loc += hist[tid * 8 + k];
  s_bsum[tid] = loc;
  __syncthreads();
  if (tid == 0) {
    unsigned int cum = 0;
    int bin = 0;
    bool fnd = false;
    for (int t = 255; t >= 0 && !fnd; t--) {
      if (cum + s_bsum[t] >= (unsigned)RANK) {
        for (int kk = 7; kk >= 0; kk--) {
          unsigned int h = hist[t * 8 + kk];
          if (cum + h >= (unsigned)RANK) { bin = t * 8 + kk; fnd = true; break; }
          cum += h;
        }
      } else {
        cum += s_bsum[t];
      }
    }
    s_cutbin = bin;
  }
  __syncthreads();
  float edge = __fmul_rn((float)s_cutbin, (1.0f / 2048.0f));  // exact

  for (int n = tid; n < NANCH; n += 256) {
    float s = sigmoid_ref(lrow[(size_t)n * 90]);
    if (s >= edge) {
      int pos = atomicAdd(&s_cnt, 1);
      if (pos < CAP) {
        s_key[pos] = __float_as_uint(s);
        s_idx[pos] = (unsigned short)n;
      }
    }
  }
  __syncthreads();
  int M = s_cnt;
  if (M > CAP) M = CAP;
  for (int e = M + tid; e < CAP; e += 256) { s_key[e] = 0u; s_idx[e] = 0xFFFFu; }
  __syncthreads();

  for (int k = 2; k <= CAP; k <<= 1) {
    for (int j = k >> 1; j > 0; j >>= 1) {
      for (int t = tid; t < CAP / 2; t += 256) {
        int i = ((t & ~(j - 1)) << 1) | (t & (j - 1));
        int p = i | j;
        unsigned int ka = s_key[i], kb = s_key[p];
        unsigned short ia = s_idx[i], ib = s_idx[p];
        bool up = ((i & k) == 0);
        bool g = (ka < kb) || (ka == kb && ia > ib);
        bool l = (kb < ka) || (ka == kb && ib > ia);
        if (up ? g : l) {
          s_key[i] = kb; s_key[p] = ka;
          s_idx[i] = ib; s_idx[p] = ia;
        }
      }
      __syncthreads();
    }
  }

  float4* cbox = (float4*)s_pool;
  int L = (M < 5000) ? M : 5000;  // PRE_NMS truncation (stable)
  for (int base = 0; base < L; base += 512) {
    int cn = min(512, L - base);
    int ns0 = s_nsel;
    if (ns0 >= POSTN) break;
    for (int t = tid; t < cn; t += 256) {
      int n = s_idx[base + t];
      float4 bx = boxes[(size_t)b * NANCH + n];
      bool al = true;
      for (int s = 0; s < ns0; s++) {
        if (iou_ref(bx, s_selbox[s]) > 0.5f) { al = false; break; }
      }
      cbox[t] = bx;
      s_alive[t] = al ? 1 : 0;
    }
    __syncthreads();
    for (int i = 0; i < cn; i++) {
      if (s_nsel >= POSTN) break;
      if (!s_alive[i]) continue;
      float4 bi = cbox[i];
      float sc = __uint_as_float(s_key[base + i]);
      if (!(iou_ref(bi, bi) > 0.5f)) {
        if (tid == 0) {
          for (int p = s_nsel; p < POSTN; p++) { s_selbox[p] = bi; s_sels[p] = sc; }
          s_nsel = POSTN;
        }
        __syncthreads();
        break;
      }
      for (int t = tid; t < cn; t += 256) {
        if (t > i && s_alive[t] && iou_ref(cbox[t], bi) > 0.5f) s_alive[t] = 0;
      }
      if (tid == 0) {
        s_selbox[s_nsel] = bi;
        s_sels[s_nsel] = sc;
        s_nsel = s_nsel + 1;
      }
      __syncthreads();
    }
    __syncthreads();
    if (s_nsel >= POSTN) break;
  }
  __syncthreads();
  int ns = s_nsel;
  for (int p = tid; p < POSTN; p += 256) {
    float sc = 0.0f;
    float4 bx = make_float4(0.0f, 0.0f, 0.0f, 0.0f);
    if (p < ns) {
      float s0 = s_sels[p];
      if (s0 > 0.2f) { sc = s0; bx = s_selbox[p]; }
    }
    sel_s[bc * POSTN + p] = sc;
    sel_b[bc * POSTN + p] = bx;
  }
}

// ---------------- per-batch top-100: histogram cut + bitonic (parallel) --------
// (verbatim R14-passing kernel)

__global__ __launch_bounds__(256) void k_final(const float* __restrict__ sel_s,
                                               const float4* __restrict__ sel_b,
                                               float* __restrict__ out) {
  int b = blockIdx.x;
  int tid = threadIdx.x;
  __shared__ __align__(16) unsigned char pool[36864];
  __shared__ unsigned int win_k[POSTN];
  __shared__ int win_e[POSTN];
  __shared__ unsigned int csum[256];
  __shared__ int s_cut, s_cnt;

  const float* srow = sel_s + (size_t)b * 9000;
  unsigned int* hist = (unsigned int*)pool;                        // [4096]
  unsigned long long* ckey = (unsigned long long*)(pool + 16384);  // [512]

  for (int e = tid; e < 4096; e += 256) hist[e] = 0u;
  if (tid == 0) s_cnt = 0;
  __syncthreads();

  // monotone bin: scores in [0.5,1] get 2^-12-mantissa resolution (2048 bins),
  // below 0.5 coarse (bits>>20 < 1008 < 2048). bin(1.0f) clamps to 4095.
  for (int e = tid; e < 9000; e += 256) {
    unsigned int bits = __float_as_uint(srow[e]);
    int bin = (bits >= 0x3F000000u)
                  ? min(4095, (int)(2048u + ((bits - 0x3F000000u) >> 12)))
                  : (int)(bits >> 20);
    atomicAdd(&hist[bin], 1u);
  }
  __syncthreads();

  unsigned int loc = 0;
#pragma unroll
  for (int k = 0; k < 16; k++) loc += hist[tid * 16 + k];
  csum[tid] = loc;
  __syncthreads();

  if (tid == 0) {
    unsigned int cum = 0;
    int cut = 0;
    bool fnd = false;
    for (int t = 255; t >= 0 && !fnd; t--) {
      if (cum + csum[t] >= (unsigned)POSTN) {
        for (int kk = 15; kk >= 0; kk--) {
          int bn = t * 16 + kk;
          unsigned int h = hist[bn];
          if (cum + h >= (unsigned)POSTN) { cut = bn; fnd = true; break; }
          cum += h;
        }
      } else {
        cum += csum[t];
      }
    }
    s_cut = cut;  // 9000 entries >= 100 -> always found
  }
  __syncthreads();
  int cut = s_cut;

  for (int e = tid; e < 9000; e += 256) {
    unsigned int bits = __float_as_uint(srow[e]);
    int bin = (bits >= 0x3F000000u)
                  ? min(4095, (int)(2048u + ((bits - 0x3F000000u) >> 12)))
                  : (int)(bits >> 20);
    if (bin >= cut) {
      int pos = atomicAdd(&s_cnt, 1);
      if (pos < 512)
        ckey[pos] = ((unsigned long long)bits << 32) | (unsigned int)(16383 - e);
    }
  }
  __syncthreads();
  int cnt = s_cnt;

  if (cnt <= 512) {
    int SN = (cnt <= 256) ? 256 : 512;
    for (int e = tid; e < SN; e += 256)
      if (e >= cnt) ckey[e] = 0ull;  // pads sort below all real keys
    __syncthreads();
    for (int k = 2; k <= SN; k <<= 1) {
      for (int j = k >> 1; j > 0; j >>= 1) {
        int t = tid;
        if (t < (SN >> 1)) {
          int i = ((t & ~(j - 1)) << 1) | (t & (j - 1));
          int p = i | j;
          unsigned long long a = ckey[i], bb = ckey[p];
          bool up = ((i & k) == 0);
          if (up ? (a < bb) : (a > bb)) { ckey[i] = bb; ckey[p] = a; }
        }
        __syncthreads();
      }
    }
    if (tid < POSTN) {
      unsigned long long v = ckey[tid];
      win_k[tid] = (unsigned int)(v >> 32);
      win_e[tid] = 16383 - (int)(v & 0x3FFFull);
    }
  } else {
    // overflow (statistically never): R4-proven serial frontier merge
    float* key = (float*)pool;                                      // [9000]
    int* ptr = (int*)(pool + 36032);                                // [90]
    unsigned long long* wred = (unsigned long long*)(pool + 36416); // [4]
    for (int e = tid; e < 9000; e += 256) key[e] = srow[e];
    if (tid < NC) ptr[tid] = 0;
    __syncthreads();
    int lane = tid & 63, wid = tid >> 6;
    for (int p = 0; p < POSTN; p++) {
      unsigned long long v = 0ull;
      if (tid < NC) {
        int pp = ptr[tid];
        if (pp < POSTN) {
          int e = tid * POSTN + pp;
          v = ((unsigned long long)__float_as_uint(key[e]) << 32) |
              (unsigned int)(16383 - e);
        }
      }
      for (int d = 32; d > 0; d >>= 1) {
        unsigned long long o = __shfl_down(v, (unsigned)d, 64);
        if (o > v) v = o;
      }
      if (lane == 0) wred[wid] = v;
      __syncthreads();
      if (tid == 0) {
        unsigned long long w2 = wred[0];
        if (wred[1] > w2) w2 = wred[1];
        int e = 16383 - (int)(w2 & 0x3FFFull);
        win_k[p] = (unsigned int)(w2 >> 32);
        win_e[p] = e;
        ptr[e / POSTN] = (e % POSTN) + 1;
      }
      __syncthreads();
    }
  }
  __syncthreads();

  for (int p = tid; p < POSTN; p += 256) {
    unsigned int k = win_k[p];
    int e = win_e[p];
    float4 bx = sel_b[(size_t)b * 9000 + e];
    ((float4*)out)[b * POSTN + p] = bx;              // out_b [8,100,4]
    out[3200 + b * POSTN + p] = __uint_as_float(k);  // out_s [8,100]
    out[4000 + b * POSTN + p] = (float)(e / POSTN);  // out_c [8,100]
  }
  if (tid == 0) {
    int v = 0;
    for (int p = 0; p < POSTN; p++) v += (win_k[p] != 0u) ? 1 : 0;
    out[4800 + b] = (float)v;  // valid [8]
  }
}

// ------------------------------- launcher --------------------------------------

extern "C" void kernel_launch(void* const* d_in, const int* in_sizes, int n_in,
                              void* d_out, int out_size, void* d_ws, size_t ws_size,
                              hipStream_t stream) {
  const float* deltas = (const float*)d_in[0];  // [8,49104,4]
  const float* logits = (const float*)d_in[1];  // [8,49104,90]
  float* out = (float*)d_out;
  char* ws = (char*)d_ws;

  size_t off = 0;
  auto take = [&](size_t bytes) -> char* {
    char* p = ws + off;
    off += (bytes + 255) & ~(size_t)255;
    return p;
  };
  // small/required buffers first so the degraded path fits in ~8.6 MB
  float4* anchors = (float4*)take((size_t)NANCH * 16);
  float4* boxes = (float4*)take((size_t)NB * NANCH * 16);
  float* sel_s = (float*)take((size_t)NBC * POSTN * 4);
  float4* sel_b = (float4*)take((size_t)NBC * POSTN * 16);
  int* flags = (int*)take((size_t)NBC * 4);
  unsigned int* gcnt = (unsigned int*)take((size_t)NBC * 4);
  unsigned int* oflow = (unsigned int*)take((size_t)NBC * 4);
  unsigned long long* gcand =
      (unsigned long long*)take((size_t)NBC * T1CAP * 8);
  bool fits = (off <= ws_size);  // total ~11.5 MB

  k_anchors<<<dim3((NANCH + 255) / 256), dim3(256), 0, stream>>>(anchors, gcnt,
                                                                 oflow);
  k_decode<<<dim3((NB * NANCH + 255) / 256), dim3(256), 0, stream>>>(
      (const float4*)deltas, anchors, boxes);
  if (fits) {
    k_scan<<<dim3(NCH, NB), dim3(256), 0, stream>>>((const float4*)logits,
                                                    gcand, gcnt, oflow);
    k_nms_t1<<<dim3(NBC), dim3(256), 0, stream>>>(gcand, gcnt, oflow, boxes,
                                                  sel_s, sel_b, flags);
  } else {
    k_flagall<<<dim3((NBC + 255) / 256), dim3(256), 0, stream>>>(flags);
  }
  k_nms_fb<8192, 5000><<<dim3(NBC), dim3(256), 0, stream>>>(logits, boxes,
                                                            sel_s, sel_b, flags);
  k_final<<<dim3(NB), dim3(256), 0, stream>>>(sel_s, sel_b, out);
}